// Round 1
// baseline (1202.142 us; speedup 1.0000x reference)
//
#include <hip/hip_runtime.h>
#include <cmath>

// ---------------- CSR build ----------------

__global__ __launch_bounds__(256) void count_k(const int* __restrict__ dst,
                                               int* __restrict__ cnt, int E) {
  int e = blockIdx.x * 256 + threadIdx.x;
  if (e < E) atomicAdd(&cnt[dst[e]], 1);
}

__global__ __launch_bounds__(256) void dinv_k(const int* __restrict__ cnt,
                                              float* __restrict__ dinv,
                                              float* __restrict__ dinv2, int N) {
  int i = blockIdx.x * 256 + threadIdx.x;
  if (i < N) {
    float deg = 1.0f + (float)cnt[i];
    dinv[i] = rsqrtf(deg);
    dinv2[i] = 1.0f / deg;
  }
}

// block-local exclusive scan of cnt -> rs, block totals -> bsum
__global__ __launch_bounds__(512) void scan_a(const int* __restrict__ cnt,
                                              int* __restrict__ rs,
                                              int* __restrict__ bsum, int n) {
  __shared__ int s[512];
  int tid = threadIdx.x;
  int gid = blockIdx.x * 512 + tid;
  int v = (gid < n) ? cnt[gid] : 0;
  s[tid] = v;
  __syncthreads();
  for (int off = 1; off < 512; off <<= 1) {
    int t = (tid >= off) ? s[tid - off] : 0;
    __syncthreads();
    s[tid] += t;
    __syncthreads();
  }
  if (gid < n) rs[gid] = s[tid] - v;  // exclusive within block
  if (tid == 511) bsum[blockIdx.x] = s[511];
}

// exclusive scan of block totals (nb <= 256)
__global__ __launch_bounds__(256) void scan_b(const int* __restrict__ bsum,
                                              int* __restrict__ boff, int nb) {
  __shared__ int s[256];
  int tid = threadIdx.x;
  int v = (tid < nb) ? bsum[tid] : 0;
  s[tid] = v;
  __syncthreads();
  for (int off = 1; off < 256; off <<= 1) {
    int t = (tid >= off) ? s[tid - off] : 0;
    __syncthreads();
    s[tid] += t;
    __syncthreads();
  }
  if (tid < nb) boff[tid] = s[tid] - v;
}

__global__ __launch_bounds__(512) void scan_c(const int* __restrict__ boff,
                                              int* __restrict__ rs, int n, int E) {
  int gid = blockIdx.x * 512 + threadIdx.x;
  if (gid < n) rs[gid] += boff[blockIdx.x];
  if (gid == 0) rs[n] = E;
}

__global__ __launch_bounds__(256) void fill_k(const int* __restrict__ src,
                                              const int* __restrict__ dst,
                                              const int* __restrict__ rs,
                                              int* __restrict__ cursor,
                                              const float* __restrict__ dinv,
                                              int* __restrict__ col,
                                              float* __restrict__ normv, int E) {
  int e = blockIdx.x * 256 + threadIdx.x;
  if (e >= E) return;
  int s = src[e], d = dst[e];
  int pos = rs[d] + atomicAdd(&cursor[d], 1);
  col[pos] = s;
  normv[pos] = dinv[s] * dinv[d];
}

// ---------------- dense GEMM: O[M,128] = A[M,128] @ W[128,128] ----------------
// 64-row tile per block, W + transposed-A staged in LDS, 8x4 thread tile.

__global__ __launch_bounds__(256) void gemm128(const float* __restrict__ A,
                                               const float* __restrict__ W,
                                               float* __restrict__ O, int M) {
  __shared__ float Ws[128 * 128];
  __shared__ float At[128][68];  // [k][r], padded to dodge bank conflicts
  int tid = threadIdx.x;
  int row0 = blockIdx.x * 64;

  const float4* W4 = (const float4*)W;
  float4* Ws4 = (float4*)Ws;
#pragma unroll
  for (int i = 0; i < 16; ++i) Ws4[tid + i * 256] = W4[tid + i * 256];

#pragma unroll
  for (int i = 0; i < 8; ++i) {
    int idx = tid + i * 256;  // 0..2047 float4s of the 64x128 tile
    int r = idx >> 5;
    int kq = idx & 31;
    int gr = row0 + r;
    float4 v = make_float4(0.f, 0.f, 0.f, 0.f);
    if (gr < M) v = ((const float4*)A)[(size_t)gr * 32 + kq];
    At[kq * 4 + 0][r] = v.x;
    At[kq * 4 + 1][r] = v.y;
    At[kq * 4 + 2][r] = v.z;
    At[kq * 4 + 3][r] = v.w;
  }
  __syncthreads();

  int tx = tid & 31, ty = tid >> 5;  // 32 col-groups x 8 row-groups
  int c0 = tx * 4, r0 = ty * 8;
  float acc[8][4] = {};
#pragma unroll 4
  for (int k = 0; k < 128; ++k) {
    float4 w = *(const float4*)&Ws[k * 128 + c0];
    float4 a0 = *(const float4*)&At[k][r0];
    float4 a1 = *(const float4*)&At[k][r0 + 4];
    float a[8] = {a0.x, a0.y, a0.z, a0.w, a1.x, a1.y, a1.z, a1.w};
#pragma unroll
    for (int i = 0; i < 8; ++i) {
      acc[i][0] += a[i] * w.x;
      acc[i][1] += a[i] * w.y;
      acc[i][2] += a[i] * w.z;
      acc[i][3] += a[i] * w.w;
    }
  }
#pragma unroll
  for (int i = 0; i < 8; ++i) {
    int gr = row0 + r0 + i;
    if (gr < M) {
      float4 v = make_float4(acc[i][0], acc[i][1], acc[i][2], acc[i][3]);
      *(float4*)&O[(size_t)gr * 128 + c0] = v;
    }
  }
}

// ---------------- fused neighbor-gather + self-loop + bias + tanh ----------------
// one wave (64 lanes) per node; lane owns 2 features (float2)

__global__ __launch_bounds__(256) void gather_k(const float* __restrict__ h,
                                                const int* __restrict__ rs,
                                                const int* __restrict__ col,
                                                const float* __restrict__ normv,
                                                const float* __restrict__ dinv2,
                                                const float* __restrict__ bias,
                                                float* __restrict__ out, int N) {
  int wave = (int)((blockIdx.x * (size_t)blockDim.x + threadIdx.x) >> 6);
  int lane = threadIdx.x & 63;
  if (wave >= N) return;
  int s = rs[wave], e = rs[wave + 1];
  const float2* h2 = (const float2*)h;
  float ax = 0.f, ay = 0.f;
  for (int p = s; p < e; ++p) {
    int srcn = col[p];
    float w = normv[p];
    float2 v = h2[(size_t)srcn * 64 + lane];
    ax += w * v.x;
    ay += w * v.y;
  }
  float d2 = dinv2[wave];
  float2 hv = h2[(size_t)wave * 64 + lane];
  float2 bv = ((const float2*)bias)[lane];
  ax = tanhf(ax + hv.x * d2 + bv.x);
  ay = tanhf(ay + hv.y * d2 + bv.y);
  float2 o;
  o.x = ax;
  o.y = ay;
  ((float2*)out)[(size_t)wave * 64 + lane] = o;
}

// ---------------- pooling ----------------

__global__ __launch_bounds__(128) void bounds_k(const int* __restrict__ batch,
                                                int* __restrict__ gstart, int n,
                                                int G) {
  int t = threadIdx.x;
  if (t > G) return;
  int lo = 0, hi = n;
  while (lo < hi) {
    int mid = (lo + hi) >> 1;
    if (batch[mid] < t) lo = mid + 1;
    else hi = mid;
  }
  gstart[t] = lo;
}

#define CH 16

__global__ __launch_bounds__(128) void pool_partial(const float* __restrict__ h,
                                                    const int* __restrict__ gstart,
                                                    float* __restrict__ pmax,
                                                    float* __restrict__ psum) {
  int g = blockIdx.x, c = blockIdx.y, f = threadIdx.x;
  int s = gstart[g], e = gstart[g + 1];
  long long len = e - s;
  int cs = s + (int)(len * c / CH);
  int ce = s + (int)(len * (c + 1) / CH);
  float m = -INFINITY, sum = 0.f;
  for (int n = cs; n < ce; ++n) {
    float v = h[(size_t)n * 128 + f];
    m = fmaxf(m, v);
    sum += v;
  }
  pmax[((size_t)g * CH + c) * 128 + f] = m;
  psum[((size_t)g * CH + c) * 128 + f] = sum;
}

__global__ __launch_bounds__(128) void pool_final(const float* __restrict__ pmax,
                                                  const float* __restrict__ psum,
                                                  const int* __restrict__ gstart,
                                                  float* __restrict__ pooled) {
  int g = blockIdx.x, f = threadIdx.x;
  float m = -INFINITY, s = 0.f;
  for (int c = 0; c < CH; ++c) {
    m = fmaxf(m, pmax[((size_t)g * CH + c) * 128 + f]);
    s += psum[((size_t)g * CH + c) * 128 + f];
  }
  int cnt = gstart[g + 1] - gstart[g];
  float mean = s / fmaxf((float)cnt, 1.0f);
  pooled[(size_t)g * 256 + f] = m;
  pooled[(size_t)g * 256 + 128 + f] = mean;
}

__global__ __launch_bounds__(64) void out_mm(const float* __restrict__ pooled,
                                             const float* __restrict__ Wout,
                                             const float* __restrict__ bout,
                                             float* __restrict__ out) {
  __shared__ float p[256];
  int g = blockIdx.x, t = threadIdx.x;
  for (int i = t; i < 256; i += 64) p[i] = pooled[(size_t)g * 256 + i];
  __syncthreads();
  if (t < 10) {
    float acc = bout[t];
    for (int k = 0; k < 256; ++k) acc += p[k] * Wout[k * 10 + t];
    out[(size_t)g * 10 + t] = acc;
  }
}

// ---------------- launch ----------------

extern "C" void kernel_launch(void* const* d_in, const int* in_sizes, int n_in,
                              void* d_out, int out_size, void* d_ws, size_t ws_size,
                              hipStream_t stream) {
  const float* x = (const float*)d_in[0];
  const int* ei = (const int*)d_in[1];
  const int* batch = (const int*)d_in[2];
  const float* W[4] = {(const float*)d_in[3], (const float*)d_in[5],
                       (const float*)d_in[7], (const float*)d_in[9]};
  const float* Bz[4] = {(const float*)d_in[4], (const float*)d_in[6],
                        (const float*)d_in[8], (const float*)d_in[10]};
  const float* Wout = (const float*)d_in[11];
  const float* bout = (const float*)d_in[12];
  const int N = in_sizes[0] / 128;
  const int E = in_sizes[1] / 2;
  const int G = 64;
  const int* srcp = ei;
  const int* dstp = ei + E;
  float* out = (float*)d_out;

  char* wsb = (char*)d_ws;
  size_t off = 0;
  auto alloc = [&](size_t bytes) -> void* {
    void* p = wsb + off;
    off = (off + bytes + 255) & ~(size_t)255;
    return p;
  };
  float* bufA = (float*)alloc((size_t)N * 128 * 4);
  float* bufB = (float*)alloc((size_t)N * 128 * 4);
  int* cnt = (int*)alloc((size_t)N * 4);
  int* cursor = (int*)alloc((size_t)N * 4);
  float* dinv = (float*)alloc((size_t)N * 4);
  float* dinv2 = (float*)alloc((size_t)N * 4);
  int* rs = (int*)alloc((size_t)(N + 1) * 4);
  int* col = (int*)alloc((size_t)E * 4);
  float* normv = (float*)alloc((size_t)E * 4);
  int* bsum = (int*)alloc(4096);
  int* boff = (int*)alloc(4096);
  int* gstart = (int*)alloc(4096);
  float* pmax = (float*)alloc((size_t)G * CH * 128 * 4);
  float* psum = (float*)alloc((size_t)G * CH * 128 * 4);
  if (off > ws_size) return;  // workspace too small; bail (will fail validation loudly)

  hipMemsetAsync(cnt, 0, (size_t)N * 4, stream);
  hipMemsetAsync(cursor, 0, (size_t)N * 4, stream);

  count_k<<<(E + 255) / 256, 256, 0, stream>>>(dstp, cnt, E);
  dinv_k<<<(N + 255) / 256, 256, 0, stream>>>(cnt, dinv, dinv2, N);
  int nsb = (N + 511) / 512;
  scan_a<<<nsb, 512, 0, stream>>>(cnt, rs, bsum, N);
  scan_b<<<1, 256, 0, stream>>>(bsum, boff, nsb);
  scan_c<<<nsb, 512, 0, stream>>>(boff, rs, N, E);
  fill_k<<<(E + 255) / 256, 256, 0, stream>>>(srcp, dstp, rs, cursor, dinv, col,
                                              normv, E);
  bounds_k<<<1, 128, 0, stream>>>(batch, gstart, N, G);

  const float* in = x;
  for (int l = 0; l < 4; ++l) {
    gemm128<<<(N + 63) / 64, 256, 0, stream>>>(in, W[l], bufA, N);
    int nwaves = N;
    gather_k<<<(nwaves * 64 + 255) / 256, 256, 0, stream>>>(bufA, rs, col, normv,
                                                            dinv2, Bz[l], bufB, N);
    in = bufB;
  }

  pool_partial<<<dim3(G, CH), 128, 0, stream>>>(bufB, gstart, pmax, psum);
  pool_final<<<G, 128, 0, stream>>>(pmax, psum, gstart, out + G * 10);
  out_mm<<<G, 64, 0, stream>>>(out + G * 10, Wout, bout, out);
}

// Round 2
// 782.594 us; speedup vs baseline: 1.5361x; 1.5361x over previous
//
#include <hip/hip_runtime.h>
#include <cmath>

typedef __attribute__((ext_vector_type(8))) short short8;
typedef __attribute__((ext_vector_type(8))) unsigned short ushort8;
typedef __attribute__((ext_vector_type(4))) float f32x4;

// ---------------- CSR build ----------------

__global__ __launch_bounds__(256) void count_k(const int* __restrict__ dst,
                                               int* __restrict__ cnt, int E) {
  int e = blockIdx.x * 256 + threadIdx.x;
  if (e < E) atomicAdd(&cnt[dst[e]], 1);
}

__global__ __launch_bounds__(256) void dinv_k(const int* __restrict__ cnt,
                                              float* __restrict__ dinv,
                                              float* __restrict__ dinv2, int N) {
  int i = blockIdx.x * 256 + threadIdx.x;
  if (i < N) {
    float deg = 1.0f + (float)cnt[i];
    dinv[i] = rsqrtf(deg);
    dinv2[i] = 1.0f / deg;
  }
}

__global__ __launch_bounds__(512) void scan_a(const int* __restrict__ cnt,
                                              int* __restrict__ rs,
                                              int* __restrict__ bsum, int n) {
  __shared__ int s[512];
  int tid = threadIdx.x;
  int gid = blockIdx.x * 512 + tid;
  int v = (gid < n) ? cnt[gid] : 0;
  s[tid] = v;
  __syncthreads();
  for (int off = 1; off < 512; off <<= 1) {
    int t = (tid >= off) ? s[tid - off] : 0;
    __syncthreads();
    s[tid] += t;
    __syncthreads();
  }
  if (gid < n) rs[gid] = s[tid] - v;
  if (tid == 511) bsum[blockIdx.x] = s[511];
}

__global__ __launch_bounds__(256) void scan_b(const int* __restrict__ bsum,
                                              int* __restrict__ boff, int nb) {
  __shared__ int s[256];
  int tid = threadIdx.x;
  int v = (tid < nb) ? bsum[tid] : 0;
  s[tid] = v;
  __syncthreads();
  for (int off = 1; off < 256; off <<= 1) {
    int t = (tid >= off) ? s[tid - off] : 0;
    __syncthreads();
    s[tid] += t;
    __syncthreads();
  }
  if (tid < nb) boff[tid] = s[tid] - v;
}

__global__ __launch_bounds__(512) void scan_c(const int* __restrict__ boff,
                                              int* __restrict__ rs, int n, int E) {
  int gid = blockIdx.x * 512 + threadIdx.x;
  if (gid < n) rs[gid] += boff[blockIdx.x];
  if (gid == 0) rs[n] = E;
}

__global__ __launch_bounds__(256) void fill_k(const int* __restrict__ src,
                                              const int* __restrict__ dst,
                                              const int* __restrict__ rs,
                                              int* __restrict__ cursor,
                                              const float* __restrict__ dinv,
                                              int* __restrict__ col,
                                              float* __restrict__ normv, int E) {
  int e = blockIdx.x * 256 + threadIdx.x;
  if (e >= E) return;
  int s = src[e], d = dst[e];
  int pos = rs[d] + atomicAdd(&cursor[d], 1);
  col[pos] = s;
  normv[pos] = dinv[s] * dinv[d];
}

// ---------------- W -> transposed split-bf16 ----------------
// WtHi/WtLo are [n][k] (transposed), bf16 hi/lo split of f32 W[k][n].

__global__ __launch_bounds__(256) void wconv_k(const float* __restrict__ W,
                                               unsigned short* __restrict__ WtHi,
                                               unsigned short* __restrict__ WtLo) {
  int t = blockIdx.x * 256 + threadIdx.x;
  if (t >= 16384) return;
  int k = t >> 7, n = t & 127;
  float w = W[t];
  unsigned int u = __float_as_uint(w);
  unsigned short hb = (unsigned short)((u + 0x7FFFu + ((u >> 16) & 1u)) >> 16);
  float hf = __uint_as_float(((unsigned int)hb) << 16);
  float lf = w - hf;
  unsigned int ul = __float_as_uint(lf);
  unsigned short lb = (unsigned short)((ul + 0x7FFFu + ((ul >> 16) & 1u)) >> 16);
  WtHi[n * 128 + k] = hb;
  WtLo[n * 128 + k] = lb;
}

// ---------------- MFMA GEMM: O[M,128] = A[M,128] @ W[128,128] ----------------
// split-bf16 (hi+lo) x3 MFMA; block = 4 waves x 32 rows = 128 rows.

#define LDK 136  // padded k-stride (ushorts): 272B rows -> ~2-way LDS banks

__global__ __launch_bounds__(256) void gemm_mfma(const float* __restrict__ A,
                                                 const unsigned short* __restrict__ WtHi,
                                                 const unsigned short* __restrict__ WtLo,
                                                 float* __restrict__ O, int M) {
  __shared__ unsigned short sHi[128 * LDK];
  __shared__ unsigned short sLo[128 * LDK];
  int tid = threadIdx.x;
#pragma unroll
  for (int i = 0; i < 8; ++i) {
    int c = tid + i * 256;       // 16B chunk 0..2047
    int n = c >> 4;
    int off = (c & 15) * 8;
    *(ushort8*)&sHi[n * LDK + off] = *(const ushort8*)&WtHi[c * 8];
    *(ushort8*)&sLo[n * LDK + off] = *(const ushort8*)&WtLo[c * 8];
  }
  __syncthreads();

  int wv = tid >> 6, lane = tid & 63;
  int r0 = blockIdx.x * 128 + wv * 32;
  int lrow = lane & 15, lk = (lane >> 4) * 8;

  f32x4 acc[2][8] = {};
#pragma unroll
  for (int kk = 0; kk < 4; ++kk) {
    int k0 = kk * 32 + lk;
    short8 ahi[2], alo[2];
#pragma unroll
    for (int fr = 0; fr < 2; ++fr) {
      int row = r0 + fr * 16 + lrow;
      row = row < M ? row : M - 1;
      const float* ap = &A[(size_t)row * 128 + k0];
      float4 a0 = *(const float4*)ap;
      float4 a1 = *(const float4*)(ap + 4);
      float av[8] = {a0.x, a0.y, a0.z, a0.w, a1.x, a1.y, a1.z, a1.w};
      union { short8 v; unsigned short u[8]; } h_, l_;
#pragma unroll
      for (int j = 0; j < 8; ++j) {
        unsigned int u = __float_as_uint(av[j]);
        unsigned short hb = (unsigned short)((u + 0x7FFFu + ((u >> 16) & 1u)) >> 16);
        float hf = __uint_as_float(((unsigned int)hb) << 16);
        float lf = av[j] - hf;
        unsigned int ul = __float_as_uint(lf);
        h_.u[j] = hb;
        l_.u[j] = (unsigned short)((ul + 0x7FFFu + ((ul >> 16) & 1u)) >> 16);
      }
      ahi[fr] = h_.v;
      alo[fr] = l_.v;
    }
#pragma unroll
    for (int c = 0; c < 8; ++c) {
      int bidx = (c * 16 + lrow) * LDK + k0;
      short8 bhi = *(const short8*)&sHi[bidx];
      short8 blo = *(const short8*)&sLo[bidx];
#pragma unroll
      for (int fr = 0; fr < 2; ++fr) {
        acc[fr][c] = __builtin_amdgcn_mfma_f32_16x16x32_bf16(ahi[fr], bhi, acc[fr][c], 0, 0, 0);
        acc[fr][c] = __builtin_amdgcn_mfma_f32_16x16x32_bf16(ahi[fr], blo, acc[fr][c], 0, 0, 0);
        acc[fr][c] = __builtin_amdgcn_mfma_f32_16x16x32_bf16(alo[fr], bhi, acc[fr][c], 0, 0, 0);
      }
    }
  }
  // C/D: col = lane&15, row = (lane>>4)*4 + reg  [m89/m91]
#pragma unroll
  for (int fr = 0; fr < 2; ++fr) {
#pragma unroll
    for (int c = 0; c < 8; ++c) {
#pragma unroll
      for (int r = 0; r < 4; ++r) {
        int row = r0 + fr * 16 + (lane >> 4) * 4 + r;
        if (row < M) O[(size_t)row * 128 + c * 16 + (lane & 15)] = acc[fr][c][r];
      }
    }
  }
}

// ---------------- fused gather + self-loop + bias + tanh ----------------
// one wave per node; lane owns float2 of features; 4x unrolled for MLP.

__global__ __launch_bounds__(256) void gather_k(const float* __restrict__ h,
                                                const int* __restrict__ rs,
                                                const int* __restrict__ col,
                                                const float* __restrict__ normv,
                                                const float* __restrict__ dinv2,
                                                const float* __restrict__ bias,
                                                float* __restrict__ out, int N) {
  int wave = (int)((blockIdx.x * (size_t)blockDim.x + threadIdx.x) >> 6);
  int lane = threadIdx.x & 63;
  if (wave >= N) return;
  int s = rs[wave], e = rs[wave + 1];
  const float2* h2 = (const float2*)h;
  float ax = 0.f, ay = 0.f;
  int p = s;
  int e4 = s + ((e - s) & ~3);
  for (; p < e4; p += 4) {
    int c0 = col[p], c1 = col[p + 1], c2 = col[p + 2], c3 = col[p + 3];
    float w0 = normv[p], w1 = normv[p + 1], w2 = normv[p + 2], w3 = normv[p + 3];
    float2 v0 = h2[(size_t)c0 * 64 + lane];
    float2 v1 = h2[(size_t)c1 * 64 + lane];
    float2 v2 = h2[(size_t)c2 * 64 + lane];
    float2 v3 = h2[(size_t)c3 * 64 + lane];
    ax += w0 * v0.x + w1 * v1.x + w2 * v2.x + w3 * v3.x;
    ay += w0 * v0.y + w1 * v1.y + w2 * v2.y + w3 * v3.y;
  }
  for (; p < e; ++p) {
    int c = col[p];
    float w = normv[p];
    float2 v = h2[(size_t)c * 64 + lane];
    ax += w * v.x;
    ay += w * v.y;
  }
  float d2 = dinv2[wave];
  float2 hv = h2[(size_t)wave * 64 + lane];
  float2 bv = ((const float2*)bias)[lane];
  ax = tanhf(ax + hv.x * d2 + bv.x);
  ay = tanhf(ay + hv.y * d2 + bv.y);
  float2 o;
  o.x = ax;
  o.y = ay;
  ((float2*)out)[(size_t)wave * 64 + lane] = o;
}

// ---------------- pooling ----------------

__global__ __launch_bounds__(128) void bounds_k(const int* __restrict__ batch,
                                                int* __restrict__ gstart, int n,
                                                int G) {
  int t = threadIdx.x;
  if (t > G) return;
  int lo = 0, hi = n;
  while (lo < hi) {
    int mid = (lo + hi) >> 1;
    if (batch[mid] < t) lo = mid + 1;
    else hi = mid;
  }
  gstart[t] = lo;
}

#define CH 16

__global__ __launch_bounds__(128) void pool_partial(const float* __restrict__ h,
                                                    const int* __restrict__ gstart,
                                                    float* __restrict__ pmax,
                                                    float* __restrict__ psum) {
  int g = blockIdx.x, c = blockIdx.y, f = threadIdx.x;
  int s = gstart[g], e = gstart[g + 1];
  long long len = e - s;
  int cs = s + (int)(len * c / CH);
  int ce = s + (int)(len * (c + 1) / CH);
  float m = -INFINITY, sum = 0.f;
  for (int n = cs; n < ce; ++n) {
    float v = h[(size_t)n * 128 + f];
    m = fmaxf(m, v);
    sum += v;
  }
  pmax[((size_t)g * CH + c) * 128 + f] = m;
  psum[((size_t)g * CH + c) * 128 + f] = sum;
}

__global__ __launch_bounds__(128) void pool_final(const float* __restrict__ pmax,
                                                  const float* __restrict__ psum,
                                                  const int* __restrict__ gstart,
                                                  float* __restrict__ pooled) {
  int g = blockIdx.x, f = threadIdx.x;
  float m = -INFINITY, s = 0.f;
  for (int c = 0; c < CH; ++c) {
    m = fmaxf(m, pmax[((size_t)g * CH + c) * 128 + f]);
    s += psum[((size_t)g * CH + c) * 128 + f];
  }
  int cnt = gstart[g + 1] - gstart[g];
  float mean = s / fmaxf((float)cnt, 1.0f);
  pooled[(size_t)g * 256 + f] = m;
  pooled[(size_t)g * 256 + 128 + f] = mean;
}

__global__ __launch_bounds__(64) void out_mm(const float* __restrict__ pooled,
                                             const float* __restrict__ Wout,
                                             const float* __restrict__ bout,
                                             float* __restrict__ out) {
  __shared__ float p[256];
  int g = blockIdx.x, t = threadIdx.x;
  for (int i = t; i < 256; i += 64) p[i] = pooled[(size_t)g * 256 + i];
  __syncthreads();
  if (t < 10) {
    float acc = bout[t];
    for (int k = 0; k < 256; ++k) acc += p[k] * Wout[k * 10 + t];
    out[(size_t)g * 10 + t] = acc;
  }
}

// ---------------- launch ----------------

extern "C" void kernel_launch(void* const* d_in, const int* in_sizes, int n_in,
                              void* d_out, int out_size, void* d_ws, size_t ws_size,
                              hipStream_t stream) {
  const float* x = (const float*)d_in[0];
  const int* ei = (const int*)d_in[1];
  const int* batch = (const int*)d_in[2];
  const float* W[4] = {(const float*)d_in[3], (const float*)d_in[5],
                       (const float*)d_in[7], (const float*)d_in[9]};
  const float* Bz[4] = {(const float*)d_in[4], (const float*)d_in[6],
                        (const float*)d_in[8], (const float*)d_in[10]};
  const float* Wout = (const float*)d_in[11];
  const float* bout = (const float*)d_in[12];
  const int N = in_sizes[0] / 128;
  const int E = in_sizes[1] / 2;
  const int G = 64;
  const int* srcp = ei;
  const int* dstp = ei + E;
  float* out = (float*)d_out;

  char* wsb = (char*)d_ws;
  size_t off = 0;
  auto alloc = [&](size_t bytes) -> void* {
    void* p = wsb + off;
    off = (off + bytes + 255) & ~(size_t)255;
    return p;
  };
  float* bufA = (float*)alloc((size_t)N * 128 * 4);
  float* bufB = (float*)alloc((size_t)N * 128 * 4);
  int* cnt = (int*)alloc((size_t)N * 4);
  int* cursor = (int*)alloc((size_t)N * 4);
  float* dinv = (float*)alloc((size_t)N * 4);
  float* dinv2 = (float*)alloc((size_t)N * 4);
  int* rs = (int*)alloc((size_t)(N + 1) * 4);
  int* col = (int*)alloc((size_t)E * 4);
  float* normv = (float*)alloc((size_t)E * 4);
  int* bsum = (int*)alloc(4096);
  int* boff = (int*)alloc(4096);
  int* gstart = (int*)alloc(4096);
  float* pmax = (float*)alloc((size_t)G * CH * 128 * 4);
  float* psum = (float*)alloc((size_t)G * CH * 128 * 4);
  unsigned short* WtHi = (unsigned short*)alloc(16384 * 2);
  unsigned short* WtLo = (unsigned short*)alloc(16384 * 2);
  if (off > ws_size) return;

  hipMemsetAsync(cnt, 0, (size_t)N * 4, stream);
  hipMemsetAsync(cursor, 0, (size_t)N * 4, stream);

  count_k<<<(E + 255) / 256, 256, 0, stream>>>(dstp, cnt, E);
  dinv_k<<<(N + 255) / 256, 256, 0, stream>>>(cnt, dinv, dinv2, N);
  int nsb = (N + 511) / 512;
  scan_a<<<nsb, 512, 0, stream>>>(cnt, rs, bsum, N);
  scan_b<<<1, 256, 0, stream>>>(bsum, boff, nsb);
  scan_c<<<nsb, 512, 0, stream>>>(boff, rs, N, E);
  fill_k<<<(E + 255) / 256, 256, 0, stream>>>(srcp, dstp, rs, cursor, dinv, col,
                                              normv, E);
  bounds_k<<<1, 128, 0, stream>>>(batch, gstart, N, G);

  const float* in = x;
  for (int l = 0; l < 4; ++l) {
    wconv_k<<<64, 256, 0, stream>>>(W[l], WtHi, WtLo);
    gemm_mfma<<<(N + 127) / 128, 256, 0, stream>>>(in, WtHi, WtLo, bufA, N);
    gather_k<<<((size_t)N * 64 + 255) / 256, 256, 0, stream>>>(bufA, rs, col, normv,
                                                               dinv2, Bz[l], bufB, N);
    in = bufB;
  }

  pool_partial<<<dim3(G, CH), 128, 0, stream>>>(bufB, gstart, pmax, psum);
  pool_final<<<G, 128, 0, stream>>>(pmax, psum, gstart, out + G * 10);
  out_mm<<<G, 64, 0, stream>>>(out + G * 10, Wout, bout, out);
}

// Round 3
// 736.542 us; speedup vs baseline: 1.6321x; 1.0625x over previous
//
#include <hip/hip_runtime.h>
#include <cmath>

typedef __attribute__((ext_vector_type(8))) short short8;
typedef __attribute__((ext_vector_type(8))) unsigned short ushort8;
typedef __attribute__((ext_vector_type(4))) float f32x4;

// ---------------- CSR build ----------------

__global__ __launch_bounds__(256) void count_k(const int* __restrict__ dst,
                                               int* __restrict__ cnt,
                                               int* __restrict__ epos, int E) {
  int e = blockIdx.x * 256 + threadIdx.x;
  if (e < E) epos[e] = atomicAdd(&cnt[dst[e]], 1);
}

__global__ __launch_bounds__(256) void dinv_k(const int* __restrict__ cnt,
                                              float* __restrict__ dinv,
                                              float* __restrict__ dinv2, int N) {
  int i = blockIdx.x * 256 + threadIdx.x;
  if (i < N) {
    float deg = 1.0f + (float)cnt[i];
    dinv[i] = rsqrtf(deg);
    dinv2[i] = 1.0f / deg;
  }
}

__global__ __launch_bounds__(512) void scan_a(const int* __restrict__ cnt,
                                              int* __restrict__ rs,
                                              int* __restrict__ bsum, int n) {
  __shared__ int s[512];
  int tid = threadIdx.x;
  int gid = blockIdx.x * 512 + tid;
  int v = (gid < n) ? cnt[gid] : 0;
  s[tid] = v;
  __syncthreads();
  for (int off = 1; off < 512; off <<= 1) {
    int t = (tid >= off) ? s[tid - off] : 0;
    __syncthreads();
    s[tid] += t;
    __syncthreads();
  }
  if (gid < n) rs[gid] = s[tid] - v;
  if (tid == 511) bsum[blockIdx.x] = s[511];
}

__global__ __launch_bounds__(256) void scan_b(const int* __restrict__ bsum,
                                              int* __restrict__ boff, int nb) {
  __shared__ int s[256];
  int tid = threadIdx.x;
  int v = (tid < nb) ? bsum[tid] : 0;
  s[tid] = v;
  __syncthreads();
  for (int off = 1; off < 256; off <<= 1) {
    int t = (tid >= off) ? s[tid - off] : 0;
    __syncthreads();
    s[tid] += t;
    __syncthreads();
  }
  if (tid < nb) boff[tid] = s[tid] - v;
}

__global__ __launch_bounds__(512) void scan_c(const int* __restrict__ boff,
                                              int* __restrict__ rs, int n, int E) {
  int gid = blockIdx.x * 512 + threadIdx.x;
  if (gid < n) rs[gid] += boff[blockIdx.x];
  if (gid == 0) rs[n] = E;
}

__global__ __launch_bounds__(256) void fill_k(const int* __restrict__ src,
                                              const int* __restrict__ dst,
                                              const int* __restrict__ rs,
                                              const int* __restrict__ epos,
                                              const float* __restrict__ dinv,
                                              int* __restrict__ col,
                                              float* __restrict__ normv, int E) {
  int e = blockIdx.x * 256 + threadIdx.x;
  if (e >= E) return;
  int s = src[e], d = dst[e];
  int pos = rs[d] + epos[e];
  col[pos] = s;
  normv[pos] = dinv[s] * dinv[d];
}

// ---------------- W -> transposed split-bf16 (all 4 layers, one launch) ----

__global__ __launch_bounds__(256) void wconv_all(const float* __restrict__ W0,
                                                 const float* __restrict__ W1,
                                                 const float* __restrict__ W2,
                                                 const float* __restrict__ W3,
                                                 unsigned short* __restrict__ WtHi,
                                                 unsigned short* __restrict__ WtLo) {
  int l = blockIdx.y;
  const float* W = (l == 0) ? W0 : (l == 1) ? W1 : (l == 2) ? W2 : W3;
  int t = blockIdx.x * 256 + threadIdx.x;
  if (t >= 16384) return;
  int k = t >> 7, n = t & 127;
  float w = W[t];
  unsigned int u = __float_as_uint(w);
  unsigned short hb = (unsigned short)((u + 0x7FFFu + ((u >> 16) & 1u)) >> 16);
  float hf = __uint_as_float(((unsigned int)hb) << 16);
  float lf = w - hf;
  unsigned int ul = __float_as_uint(lf);
  unsigned short lb = (unsigned short)((ul + 0x7FFFu + ((ul >> 16) & 1u)) >> 16);
  WtHi[l * 16384 + n * 128 + k] = hb;
  WtLo[l * 16384 + n * 128 + k] = lb;
}

// ---------------- MFMA GEMM: O[M,128] = A[M,128] @ W[128,128] ----------------

#define LDK 136

__global__ __launch_bounds__(256) void gemm_mfma(const float* __restrict__ A,
                                                 const unsigned short* __restrict__ WtHi,
                                                 const unsigned short* __restrict__ WtLo,
                                                 float* __restrict__ O, int M) {
  __shared__ unsigned short sHi[128 * LDK];
  __shared__ unsigned short sLo[128 * LDK];
  int tid = threadIdx.x;
#pragma unroll
  for (int i = 0; i < 8; ++i) {
    int c = tid + i * 256;
    int n = c >> 4;
    int off = (c & 15) * 8;
    *(ushort8*)&sHi[n * LDK + off] = *(const ushort8*)&WtHi[c * 8];
    *(ushort8*)&sLo[n * LDK + off] = *(const ushort8*)&WtLo[c * 8];
  }
  __syncthreads();

  int wv = tid >> 6, lane = tid & 63;
  int r0 = blockIdx.x * 128 + wv * 32;
  int lrow = lane & 15, lk = (lane >> 4) * 8;

  f32x4 acc[2][8] = {};
#pragma unroll
  for (int kk = 0; kk < 4; ++kk) {
    int k0 = kk * 32 + lk;
    short8 ahi[2], alo[2];
#pragma unroll
    for (int fr = 0; fr < 2; ++fr) {
      int row = r0 + fr * 16 + lrow;
      row = row < M ? row : M - 1;
      const float* ap = &A[(size_t)row * 128 + k0];
      float4 a0 = *(const float4*)ap;
      float4 a1 = *(const float4*)(ap + 4);
      float av[8] = {a0.x, a0.y, a0.z, a0.w, a1.x, a1.y, a1.z, a1.w};
      union { short8 v; unsigned short u[8]; } h_, l_;
#pragma unroll
      for (int j = 0; j < 8; ++j) {
        unsigned int u = __float_as_uint(av[j]);
        unsigned short hb = (unsigned short)((u + 0x7FFFu + ((u >> 16) & 1u)) >> 16);
        float hf = __uint_as_float(((unsigned int)hb) << 16);
        float lf = av[j] - hf;
        unsigned int ul = __float_as_uint(lf);
        h_.u[j] = hb;
        l_.u[j] = (unsigned short)((ul + 0x7FFFu + ((ul >> 16) & 1u)) >> 16);
      }
      ahi[fr] = h_.v;
      alo[fr] = l_.v;
    }
#pragma unroll
    for (int c = 0; c < 8; ++c) {
      int bidx = (c * 16 + lrow) * LDK + k0;
      short8 bhi = *(const short8*)&sHi[bidx];
      short8 blo = *(const short8*)&sLo[bidx];
#pragma unroll
      for (int fr = 0; fr < 2; ++fr) {
        acc[fr][c] = __builtin_amdgcn_mfma_f32_16x16x32_bf16(ahi[fr], bhi, acc[fr][c], 0, 0, 0);
        acc[fr][c] = __builtin_amdgcn_mfma_f32_16x16x32_bf16(ahi[fr], blo, acc[fr][c], 0, 0, 0);
        acc[fr][c] = __builtin_amdgcn_mfma_f32_16x16x32_bf16(alo[fr], bhi, acc[fr][c], 0, 0, 0);
      }
    }
  }
#pragma unroll
  for (int fr = 0; fr < 2; ++fr) {
#pragma unroll
    for (int c = 0; c < 8; ++c) {
#pragma unroll
      for (int r = 0; r < 4; ++r) {
        int row = r0 + fr * 16 + (lane >> 4) * 4 + r;
        if (row < M) O[(size_t)row * 128 + c * 16 + (lane & 15)] = acc[fr][c][r];
      }
    }
  }
}

// ---------------- fused gather + self-loop + bias + tanh ----------------
// wave per node; lanes 0-31 handle even edges, 32-63 odd edges; float4/lane.
// 8 edges per main-loop iter = 4 independent 1KB loads in flight.

__global__ __launch_bounds__(256) void gather_k(const float* __restrict__ h,
                                                const int* __restrict__ rs,
                                                const int* __restrict__ col,
                                                const float* __restrict__ normv,
                                                const float* __restrict__ dinv2,
                                                const float* __restrict__ bias,
                                                float* __restrict__ out, int N) {
  int wid = (int)((blockIdx.x * (size_t)blockDim.x + threadIdx.x) >> 6);
  if (wid >= N) return;
  int lane = threadIdx.x & 63;
  int li = lane & 31;
  int half = lane >> 5;
  int s = rs[wid], e = rs[wid + 1];
  const float4* h4 = (const float4*)h;

  float ax = 0.f, ay = 0.f, az = 0.f, aw = 0.f;
  int n8 = (e - s) >> 3;  // full groups of 8 edges
  int base = s + half;
  for (int g = 0; g < n8; ++g, base += 8) {
    int c0 = col[base], c1 = col[base + 2], c2 = col[base + 4], c3 = col[base + 6];
    float w0 = normv[base], w1 = normv[base + 2], w2 = normv[base + 4],
          w3 = normv[base + 6];
    float4 v0 = h4[(size_t)c0 * 32 + li];
    float4 v1 = h4[(size_t)c1 * 32 + li];
    float4 v2 = h4[(size_t)c2 * 32 + li];
    float4 v3 = h4[(size_t)c3 * 32 + li];
    ax += w0 * v0.x + w1 * v1.x + w2 * v2.x + w3 * v3.x;
    ay += w0 * v0.y + w1 * v1.y + w2 * v2.y + w3 * v3.y;
    az += w0 * v0.z + w1 * v1.z + w2 * v2.z + w3 * v3.z;
    aw += w0 * v0.w + w1 * v1.w + w2 * v2.w + w3 * v3.w;
  }
  for (int idx = base; idx < e; idx += 2) {
    int c = col[idx];
    float w = normv[idx];
    float4 v = h4[(size_t)c * 32 + li];
    ax += w * v.x;
    ay += w * v.y;
    az += w * v.z;
    aw += w * v.w;
  }
  // combine even/odd halves (lane ^ 32)
  ax += __shfl_xor(ax, 32);
  ay += __shfl_xor(ay, 32);
  az += __shfl_xor(az, 32);
  aw += __shfl_xor(aw, 32);

  float d2 = dinv2[wid];
  float4 sv = h4[(size_t)wid * 32 + li];
  float4 bv = ((const float4*)bias)[li];
  ax = tanhf(ax + sv.x * d2 + bv.x);
  ay = tanhf(ay + sv.y * d2 + bv.y);
  az = tanhf(az + sv.z * d2 + bv.z);
  aw = tanhf(aw + sv.w * d2 + bv.w);
  if (half == 0) {
    float4 o;
    o.x = ax; o.y = ay; o.z = az; o.w = aw;
    ((float4*)out)[(size_t)wid * 32 + li] = o;
  }
}

// ---------------- pooling ----------------

__global__ __launch_bounds__(128) void bounds_k(const int* __restrict__ batch,
                                                int* __restrict__ gstart, int n,
                                                int G) {
  int t = threadIdx.x;
  if (t > G) return;
  int lo = 0, hi = n;
  while (lo < hi) {
    int mid = (lo + hi) >> 1;
    if (batch[mid] < t) lo = mid + 1;
    else hi = mid;
  }
  gstart[t] = lo;
}

#define CH 16

__global__ __launch_bounds__(128) void pool_partial(const float* __restrict__ h,
                                                    const int* __restrict__ gstart,
                                                    float* __restrict__ pmax,
                                                    float* __restrict__ psum) {
  int g = blockIdx.x, c = blockIdx.y, f = threadIdx.x;
  int s = gstart[g], e = gstart[g + 1];
  long long len = e - s;
  int cs = s + (int)(len * c / CH);
  int ce = s + (int)(len * (c + 1) / CH);
  float m = -INFINITY, sum = 0.f;
  for (int n = cs; n < ce; ++n) {
    float v = h[(size_t)n * 128 + f];
    m = fmaxf(m, v);
    sum += v;
  }
  pmax[((size_t)g * CH + c) * 128 + f] = m;
  psum[((size_t)g * CH + c) * 128 + f] = sum;
}

__global__ __launch_bounds__(128) void pool_final(const float* __restrict__ pmax,
                                                  const float* __restrict__ psum,
                                                  const int* __restrict__ gstart,
                                                  float* __restrict__ pooled) {
  int g = blockIdx.x, f = threadIdx.x;
  float m = -INFINITY, s = 0.f;
  for (int c = 0; c < CH; ++c) {
    m = fmaxf(m, pmax[((size_t)g * CH + c) * 128 + f]);
    s += psum[((size_t)g * CH + c) * 128 + f];
  }
  int cnt = gstart[g + 1] - gstart[g];
  float mean = s / fmaxf((float)cnt, 1.0f);
  pooled[(size_t)g * 256 + f] = m;
  pooled[(size_t)g * 256 + 128 + f] = mean;
}

__global__ __launch_bounds__(64) void out_mm(const float* __restrict__ pooled,
                                             const float* __restrict__ Wout,
                                             const float* __restrict__ bout,
                                             float* __restrict__ out) {
  __shared__ float p[256];
  int g = blockIdx.x, t = threadIdx.x;
  for (int i = t; i < 256; i += 64) p[i] = pooled[(size_t)g * 256 + i];
  __syncthreads();
  if (t < 10) {
    float acc = bout[t];
    for (int k = 0; k < 256; ++k) acc += p[k] * Wout[k * 10 + t];
    out[(size_t)g * 10 + t] = acc;
  }
}

// ---------------- launch ----------------

extern "C" void kernel_launch(void* const* d_in, const int* in_sizes, int n_in,
                              void* d_out, int out_size, void* d_ws, size_t ws_size,
                              hipStream_t stream) {
  const float* x = (const float*)d_in[0];
  const int* ei = (const int*)d_in[1];
  const int* batch = (const int*)d_in[2];
  const float* W[4] = {(const float*)d_in[3], (const float*)d_in[5],
                       (const float*)d_in[7], (const float*)d_in[9]};
  const float* Bz[4] = {(const float*)d_in[4], (const float*)d_in[6],
                        (const float*)d_in[8], (const float*)d_in[10]};
  const float* Wout = (const float*)d_in[11];
  const float* bout = (const float*)d_in[12];
  const int N = in_sizes[0] / 128;
  const int E = in_sizes[1] / 2;
  const int G = 64;
  const int* srcp = ei;
  const int* dstp = ei + E;
  float* out = (float*)d_out;

  char* wsb = (char*)d_ws;
  size_t off = 0;
  auto alloc = [&](size_t bytes) -> void* {
    void* p = wsb + off;
    off = (off + bytes + 255) & ~(size_t)255;
    return p;
  };
  float* bufA = (float*)alloc((size_t)N * 128 * 4);
  float* bufB = (float*)alloc((size_t)N * 128 * 4);
  int* cnt = (int*)alloc((size_t)N * 4);
  int* epos = (int*)alloc((size_t)E * 4);
  float* dinv = (float*)alloc((size_t)N * 4);
  float* dinv2 = (float*)alloc((size_t)N * 4);
  int* rs = (int*)alloc((size_t)(N + 1) * 4);
  int* col = (int*)alloc((size_t)E * 4);
  float* normv = (float*)alloc((size_t)E * 4);
  int* bsum = (int*)alloc(4096);
  int* boff = (int*)alloc(4096);
  int* gstart = (int*)alloc(4096);
  float* pmax = (float*)alloc((size_t)G * CH * 128 * 4);
  float* psum = (float*)alloc((size_t)G * CH * 128 * 4);
  unsigned short* WtHi = (unsigned short*)alloc(4 * 16384 * 2);
  unsigned short* WtLo = (unsigned short*)alloc(4 * 16384 * 2);
  if (off > ws_size) return;

  hipMemsetAsync(cnt, 0, (size_t)N * 4, stream);

  count_k<<<(E + 255) / 256, 256, 0, stream>>>(dstp, cnt, epos, E);
  dinv_k<<<(N + 255) / 256, 256, 0, stream>>>(cnt, dinv, dinv2, N);
  int nsb = (N + 511) / 512;
  scan_a<<<nsb, 512, 0, stream>>>(cnt, rs, bsum, N);
  scan_b<<<1, 256, 0, stream>>>(bsum, boff, nsb);
  scan_c<<<nsb, 512, 0, stream>>>(boff, rs, N, E);
  fill_k<<<(E + 255) / 256, 256, 0, stream>>>(srcp, dstp, rs, epos, dinv, col,
                                              normv, E);
  bounds_k<<<1, 128, 0, stream>>>(batch, gstart, N, G);
  wconv_all<<<dim3(64, 4), 256, 0, stream>>>(W[0], W[1], W[2], W[3], WtHi, WtLo);

  const float* in = x;
  for (int l = 0; l < 4; ++l) {
    gemm_mfma<<<(N + 127) / 128, 256, 0, stream>>>(in, WtHi + l * 16384,
                                                   WtLo + l * 16384, bufA, N);
    gather_k<<<((size_t)N * 64 + 255) / 256, 256, 0, stream>>>(bufA, rs, col, normv,
                                                               dinv2, Bz[l], bufB, N);
    in = bufB;
  }

  pool_partial<<<dim3(G, CH), 128, 0, stream>>>(bufB, gstart, pmax, psum);
  pool_final<<<G, 128, 0, stream>>>(pmax, psum, gstart, out + G * 10);
  out_mm<<<G, 64, 0, stream>>>(out + G * 10, Wout, bout, out);
}

// Round 4
// 547.782 us; speedup vs baseline: 2.1946x; 1.3446x over previous
//
#include <hip/hip_runtime.h>
#include <hip/hip_fp16.h>
#include <cmath>

typedef __attribute__((ext_vector_type(8))) short short8;
typedef __attribute__((ext_vector_type(8))) unsigned short ushort8;
typedef __attribute__((ext_vector_type(4))) float f32x4;

struct h8 { __half2 a, b, c, d; };  // 16B = 8 fp16 features

// ---------------- CSR build ----------------

__global__ __launch_bounds__(256) void count_k(const int* __restrict__ dst,
                                               int* __restrict__ cnt,
                                               int* __restrict__ epos, int E) {
  int e = blockIdx.x * 256 + threadIdx.x;
  if (e < E) epos[e] = atomicAdd(&cnt[dst[e]], 1);
}

__global__ __launch_bounds__(256) void dinv_k(const int* __restrict__ cnt,
                                              float* __restrict__ dinv,
                                              float* __restrict__ dinv2, int N) {
  int i = blockIdx.x * 256 + threadIdx.x;
  if (i < N) {
    float deg = 1.0f + (float)cnt[i];
    dinv[i] = rsqrtf(deg);
    dinv2[i] = 1.0f / deg;
  }
}

__global__ __launch_bounds__(512) void scan_a(const int* __restrict__ cnt,
                                              int* __restrict__ rs,
                                              int* __restrict__ bsum, int n) {
  __shared__ int s[512];
  int tid = threadIdx.x;
  int gid = blockIdx.x * 512 + tid;
  int v = (gid < n) ? cnt[gid] : 0;
  s[tid] = v;
  __syncthreads();
  for (int off = 1; off < 512; off <<= 1) {
    int t = (tid >= off) ? s[tid - off] : 0;
    __syncthreads();
    s[tid] += t;
    __syncthreads();
  }
  if (gid < n) rs[gid] = s[tid] - v;
  if (tid == 511) bsum[blockIdx.x] = s[511];
}

__global__ __launch_bounds__(256) void scan_b(const int* __restrict__ bsum,
                                              int* __restrict__ boff, int nb) {
  __shared__ int s[256];
  int tid = threadIdx.x;
  int v = (tid < nb) ? bsum[tid] : 0;
  s[tid] = v;
  __syncthreads();
  for (int off = 1; off < 256; off <<= 1) {
    int t = (tid >= off) ? s[tid - off] : 0;
    __syncthreads();
    s[tid] += t;
    __syncthreads();
  }
  if (tid < nb) boff[tid] = s[tid] - v;
}

__global__ __launch_bounds__(512) void scan_c(const int* __restrict__ boff,
                                              int* __restrict__ rs, int n, int E) {
  int gid = blockIdx.x * 512 + threadIdx.x;
  if (gid < n) rs[gid] += boff[blockIdx.x];
  if (gid == 0) rs[n] = E;
}

__global__ __launch_bounds__(256) void fill_k(const int* __restrict__ src,
                                              const int* __restrict__ dst,
                                              const int* __restrict__ rs,
                                              const int* __restrict__ epos,
                                              const float* __restrict__ dinv,
                                              int* __restrict__ col,
                                              float* __restrict__ normv, int E) {
  int e = blockIdx.x * 256 + threadIdx.x;
  if (e >= E) return;
  int s = src[e], d = dst[e];
  int pos = rs[d] + epos[e];
  col[pos] = s;
  normv[pos] = dinv[s] * dinv[d];
}

// ---------------- W -> transposed split-bf16 (all 4 layers) ----------------

__global__ __launch_bounds__(256) void wconv_all(const float* __restrict__ W0,
                                                 const float* __restrict__ W1,
                                                 const float* __restrict__ W2,
                                                 const float* __restrict__ W3,
                                                 unsigned short* __restrict__ WtHi,
                                                 unsigned short* __restrict__ WtLo) {
  int l = blockIdx.y;
  const float* W = (l == 0) ? W0 : (l == 1) ? W1 : (l == 2) ? W2 : W3;
  int t = blockIdx.x * 256 + threadIdx.x;
  if (t >= 16384) return;
  int k = t >> 7, n = t & 127;
  float w = W[t];
  unsigned int u = __float_as_uint(w);
  unsigned short hb = (unsigned short)((u + 0x7FFFu + ((u >> 16) & 1u)) >> 16);
  float hf = __uint_as_float(((unsigned int)hb) << 16);
  float lf = w - hf;
  unsigned int ul = __float_as_uint(lf);
  unsigned short lb = (unsigned short)((ul + 0x7FFFu + ((ul >> 16) & 1u)) >> 16);
  WtHi[l * 16384 + n * 128 + k] = hb;
  WtLo[l * 16384 + n * 128 + k] = lb;
}

// ---------------- MFMA GEMM: O[M,128](fp16) = A[M,128](f32) @ W ----------------

#define LDK 136

__global__ __launch_bounds__(256) void gemm_mfma(const float* __restrict__ A,
                                                 const unsigned short* __restrict__ WtHi,
                                                 const unsigned short* __restrict__ WtLo,
                                                 __half* __restrict__ O, int M) {
  __shared__ unsigned short sHi[128 * LDK];
  __shared__ unsigned short sLo[128 * LDK];
  int tid = threadIdx.x;
#pragma unroll
  for (int i = 0; i < 8; ++i) {
    int c = tid + i * 256;
    int n = c >> 4;
    int off = (c & 15) * 8;
    *(ushort8*)&sHi[n * LDK + off] = *(const ushort8*)&WtHi[c * 8];
    *(ushort8*)&sLo[n * LDK + off] = *(const ushort8*)&WtLo[c * 8];
  }
  __syncthreads();

  int wv = tid >> 6, lane = tid & 63;
  int r0 = blockIdx.x * 128 + wv * 32;
  int lrow = lane & 15, lk = (lane >> 4) * 8;

  f32x4 acc[2][8] = {};
#pragma unroll
  for (int kk = 0; kk < 4; ++kk) {
    int k0 = kk * 32 + lk;
    short8 ahi[2], alo[2];
#pragma unroll
    for (int fr = 0; fr < 2; ++fr) {
      int row = r0 + fr * 16 + lrow;
      row = row < M ? row : M - 1;
      const float* ap = &A[(size_t)row * 128 + k0];
      float4 a0 = *(const float4*)ap;
      float4 a1 = *(const float4*)(ap + 4);
      float av[8] = {a0.x, a0.y, a0.z, a0.w, a1.x, a1.y, a1.z, a1.w};
      union { short8 v; unsigned short u[8]; } h_, l_;
#pragma unroll
      for (int j = 0; j < 8; ++j) {
        unsigned int u = __float_as_uint(av[j]);
        unsigned short hb = (unsigned short)((u + 0x7FFFu + ((u >> 16) & 1u)) >> 16);
        float hf = __uint_as_float(((unsigned int)hb) << 16);
        float lf = av[j] - hf;
        unsigned int ul = __float_as_uint(lf);
        h_.u[j] = hb;
        l_.u[j] = (unsigned short)((ul + 0x7FFFu + ((ul >> 16) & 1u)) >> 16);
      }
      ahi[fr] = h_.v;
      alo[fr] = l_.v;
    }
#pragma unroll
    for (int c = 0; c < 8; ++c) {
      int bidx = (c * 16 + lrow) * LDK + k0;
      short8 bhi = *(const short8*)&sHi[bidx];
      short8 blo = *(const short8*)&sLo[bidx];
#pragma unroll
      for (int fr = 0; fr < 2; ++fr) {
        acc[fr][c] = __builtin_amdgcn_mfma_f32_16x16x32_bf16(ahi[fr], bhi, acc[fr][c], 0, 0, 0);
        acc[fr][c] = __builtin_amdgcn_mfma_f32_16x16x32_bf16(ahi[fr], blo, acc[fr][c], 0, 0, 0);
        acc[fr][c] = __builtin_amdgcn_mfma_f32_16x16x32_bf16(alo[fr], bhi, acc[fr][c], 0, 0, 0);
      }
    }
  }
#pragma unroll
  for (int fr = 0; fr < 2; ++fr) {
#pragma unroll
    for (int c = 0; c < 8; ++c) {
#pragma unroll
      for (int r = 0; r < 4; ++r) {
        int row = r0 + fr * 16 + (lane >> 4) * 4 + r;
        if (row < M)
          O[(size_t)row * 128 + c * 16 + (lane & 15)] = __float2half(acc[fr][c][r]);
      }
    }
  }
}

// ---------------- fused gather + self-loop + bias + tanh ----------------
// wave per node; 4 lane-groups of 16; each group reads one 256B fp16 row;
// 16 edges per unrolled iter = 4 independent 16B loads per lane in flight.

__global__ __launch_bounds__(256) void gather_k(const __half* __restrict__ h,
                                                const int* __restrict__ rs,
                                                const int* __restrict__ col,
                                                const float* __restrict__ normv,
                                                const float* __restrict__ dinv2,
                                                const float* __restrict__ bias,
                                                float* __restrict__ out, int N) {
  int wid = (int)((blockIdx.x * (size_t)blockDim.x + threadIdx.x) >> 6);
  if (wid >= N) return;
  int lane = threadIdx.x & 63;
  int grp = lane >> 4;   // 0..3: edge slot
  int li = lane & 15;    // feature chunk: features [li*8, li*8+8)
  int s = rs[wid], e = rs[wid + 1];
  const h8* hrow = (const h8*)h;  // row i = hrow[i*16 + li]

  float ac[8] = {};
  int n16 = (e - s) >> 4;
  int base = s + grp;
  for (int it = 0; it < n16; ++it, base += 16) {
    int c0 = col[base], c1 = col[base + 4], c2 = col[base + 8], c3 = col[base + 12];
    float w0 = normv[base], w1 = normv[base + 4], w2 = normv[base + 8],
          w3 = normv[base + 12];
    h8 v0 = hrow[(size_t)c0 * 16 + li];
    h8 v1 = hrow[(size_t)c1 * 16 + li];
    h8 v2 = hrow[(size_t)c2 * 16 + li];
    h8 v3 = hrow[(size_t)c3 * 16 + li];
#define ACC(V, W)                                    \
    {                                                \
      float2 f0 = __half22float2((V).a);             \
      float2 f1 = __half22float2((V).b);             \
      float2 f2 = __half22float2((V).c);             \
      float2 f3 = __half22float2((V).d);             \
      ac[0] += (W) * f0.x; ac[1] += (W) * f0.y;      \
      ac[2] += (W) * f1.x; ac[3] += (W) * f1.y;      \
      ac[4] += (W) * f2.x; ac[5] += (W) * f2.y;      \
      ac[6] += (W) * f3.x; ac[7] += (W) * f3.y;      \
    }
    ACC(v0, w0) ACC(v1, w1) ACC(v2, w2) ACC(v3, w3)
  }
  for (int idx = base; idx < e; idx += 4) {
    int c = col[idx];
    float w = normv[idx];
    h8 v = hrow[(size_t)c * 16 + li];
    ACC(v, w)
  }
#undef ACC
  // combine the 4 edge-slots (feature chunks identical across groups)
#pragma unroll
  for (int j = 0; j < 8; ++j) {
    ac[j] += __shfl_xor(ac[j], 16);
    ac[j] += __shfl_xor(ac[j], 32);
  }

  float d2 = dinv2[wid];
  h8 sv = hrow[(size_t)wid * 16 + li];
  float2 s0 = __half22float2(sv.a), s1 = __half22float2(sv.b),
         s2 = __half22float2(sv.c), s3 = __half22float2(sv.d);
  float svf[8] = {s0.x, s0.y, s1.x, s1.y, s2.x, s2.y, s3.x, s3.y};
  float4 b0 = ((const float4*)bias)[li * 2];
  float4 b1 = ((const float4*)bias)[li * 2 + 1];
  float bvf[8] = {b0.x, b0.y, b0.z, b0.w, b1.x, b1.y, b1.z, b1.w};
  float o[8];
#pragma unroll
  for (int j = 0; j < 8; ++j) o[j] = tanhf(ac[j] + svf[j] * d2 + bvf[j]);
  if (grp == 0) {
    float4* op = (float4*)&out[(size_t)wid * 128 + li * 8];
    op[0] = make_float4(o[0], o[1], o[2], o[3]);
    op[1] = make_float4(o[4], o[5], o[6], o[7]);
  }
}

// ---------------- pooling ----------------

__global__ __launch_bounds__(128) void bounds_k(const int* __restrict__ batch,
                                                int* __restrict__ gstart, int n,
                                                int G) {
  int t = threadIdx.x;
  if (t > G) return;
  int lo = 0, hi = n;
  while (lo < hi) {
    int mid = (lo + hi) >> 1;
    if (batch[mid] < t) lo = mid + 1;
    else hi = mid;
  }
  gstart[t] = lo;
}

#define CH 16

__global__ __launch_bounds__(128) void pool_partial(const float* __restrict__ h,
                                                    const int* __restrict__ gstart,
                                                    float* __restrict__ pmax,
                                                    float* __restrict__ psum) {
  int g = blockIdx.x, c = blockIdx.y, f = threadIdx.x;
  int s = gstart[g], e = gstart[g + 1];
  long long len = e - s;
  int cs = s + (int)(len * c / CH);
  int ce = s + (int)(len * (c + 1) / CH);
  float m = -INFINITY, sum = 0.f;
  for (int n = cs; n < ce; ++n) {
    float v = h[(size_t)n * 128 + f];
    m = fmaxf(m, v);
    sum += v;
  }
  pmax[((size_t)g * CH + c) * 128 + f] = m;
  psum[((size_t)g * CH + c) * 128 + f] = sum;
}

__global__ __launch_bounds__(128) void pool_final(const float* __restrict__ pmax,
                                                  const float* __restrict__ psum,
                                                  const int* __restrict__ gstart,
                                                  float* __restrict__ pooled) {
  int g = blockIdx.x, f = threadIdx.x;
  float m = -INFINITY, s = 0.f;
  for (int c = 0; c < CH; ++c) {
    m = fmaxf(m, pmax[((size_t)g * CH + c) * 128 + f]);
    s += psum[((size_t)g * CH + c) * 128 + f];
  }
  int cnt = gstart[g + 1] - gstart[g];
  float mean = s / fmaxf((float)cnt, 1.0f);
  pooled[(size_t)g * 256 + f] = m;
  pooled[(size_t)g * 256 + 128 + f] = mean;
}

__global__ __launch_bounds__(64) void out_mm(const float* __restrict__ pooled,
                                             const float* __restrict__ Wout,
                                             const float* __restrict__ bout,
                                             float* __restrict__ out) {
  __shared__ float p[256];
  int g = blockIdx.x, t = threadIdx.x;
  for (int i = t; i < 256; i += 64) p[i] = pooled[(size_t)g * 256 + i];
  __syncthreads();
  if (t < 10) {
    float acc = bout[t];
    for (int k = 0; k < 256; ++k) acc += p[k] * Wout[k * 10 + t];
    out[(size_t)g * 10 + t] = acc;
  }
}

// ---------------- launch ----------------

extern "C" void kernel_launch(void* const* d_in, const int* in_sizes, int n_in,
                              void* d_out, int out_size, void* d_ws, size_t ws_size,
                              hipStream_t stream) {
  const float* x = (const float*)d_in[0];
  const int* ei = (const int*)d_in[1];
  const int* batch = (const int*)d_in[2];
  const float* W[4] = {(const float*)d_in[3], (const float*)d_in[5],
                       (const float*)d_in[7], (const float*)d_in[9]};
  const float* Bz[4] = {(const float*)d_in[4], (const float*)d_in[6],
                        (const float*)d_in[8], (const float*)d_in[10]};
  const float* Wout = (const float*)d_in[11];
  const float* bout = (const float*)d_in[12];
  const int N = in_sizes[0] / 128;
  const int E = in_sizes[1] / 2;
  const int G = 64;
  const int* srcp = ei;
  const int* dstp = ei + E;
  float* out = (float*)d_out;

  char* wsb = (char*)d_ws;
  size_t off = 0;
  auto alloc = [&](size_t bytes) -> void* {
    void* p = wsb + off;
    off = (off + bytes + 255) & ~(size_t)255;
    return p;
  };
  __half* bufA = (__half*)alloc((size_t)N * 128 * 2);   // fp16 GEMM output
  float* bufB = (float*)alloc((size_t)N * 128 * 4);     // f32 gather output
  int* cnt = (int*)alloc((size_t)N * 4);
  int* epos = (int*)alloc((size_t)E * 4);
  float* dinv = (float*)alloc((size_t)N * 4);
  float* dinv2 = (float*)alloc((size_t)N * 4);
  int* rs = (int*)alloc((size_t)(N + 1) * 4);
  int* col = (int*)alloc((size_t)E * 4);
  float* normv = (float*)alloc((size_t)E * 4);
  int* bsum = (int*)alloc(4096);
  int* boff = (int*)alloc(4096);
  int* gstart = (int*)alloc(4096);
  float* pmax = (float*)alloc((size_t)G * CH * 128 * 4);
  float* psum = (float*)alloc((size_t)G * CH * 128 * 4);
  unsigned short* WtHi = (unsigned short*)alloc(4 * 16384 * 2);
  unsigned short* WtLo = (unsigned short*)alloc(4 * 16384 * 2);
  if (off > ws_size) return;

  hipMemsetAsync(cnt, 0, (size_t)N * 4, stream);

  count_k<<<(E + 255) / 256, 256, 0, stream>>>(dstp, cnt, epos, E);
  dinv_k<<<(N + 255) / 256, 256, 0, stream>>>(cnt, dinv, dinv2, N);
  int nsb = (N + 511) / 512;
  scan_a<<<nsb, 512, 0, stream>>>(cnt, rs, bsum, N);
  scan_b<<<1, 256, 0, stream>>>(bsum, boff, nsb);
  scan_c<<<nsb, 512, 0, stream>>>(boff, rs, N, E);
  fill_k<<<(E + 255) / 256, 256, 0, stream>>>(srcp, dstp, rs, epos, dinv, col,
                                              normv, E);
  bounds_k<<<1, 128, 0, stream>>>(batch, gstart, N, G);
  wconv_all<<<dim3(64, 4), 256, 0, stream>>>(W[0], W[1], W[2], W[3], WtHi, WtLo);

  const float* in = x;
  for (int l = 0; l < 4; ++l) {
    gemm_mfma<<<(N + 127) / 128, 256, 0, stream>>>(in, WtHi + l * 16384,
                                                   WtLo + l * 16384, bufA, N);
    gather_k<<<((size_t)N * 64 + 255) / 256, 256, 0, stream>>>(bufA, rs, col, normv,
                                                               dinv2, Bz[l], bufB, N);
    in = bufB;
  }

  pool_partial<<<dim3(G, CH), 128, 0, stream>>>(bufB, gstart, pmax, psum);
  pool_final<<<G, 128, 0, stream>>>(pmax, psum, gstart, out + G * 10);
  out_mm<<<G, 64, 0, stream>>>(out + G * 10, Wout, bout, out);
}

// Round 5
// 541.258 us; speedup vs baseline: 2.2210x; 1.0121x over previous
//
#include <hip/hip_runtime.h>
#include <hip/hip_fp16.h>
#include <cmath>

typedef __attribute__((ext_vector_type(8))) short short8;
typedef __attribute__((ext_vector_type(8))) unsigned short ushort8;
typedef __attribute__((ext_vector_type(4))) float f32x4;

struct h8 { __half2 a, b, c, d; };  // 16B = 8 fp16 features

__device__ __forceinline__ unsigned pk_bf16(float a, float b) {
  unsigned r;
  asm("v_cvt_pk_bf16_f32 %0, %1, %2" : "=v"(r) : "v"(a), "v"(b));
  return r;  // lo16 = bf16(a), hi16 = bf16(b), RNE
}

__device__ __forceinline__ float fast_tanh(float x) {
  float e2 = __expf(2.0f * x);
  return 1.0f - 2.0f * __builtin_amdgcn_rcpf(e2 + 1.0f);
}

// ---------------- CSR build ----------------

__global__ __launch_bounds__(256) void count_k(const int* __restrict__ dst,
                                               int* __restrict__ cnt,
                                               int* __restrict__ epos, int E) {
  int e = blockIdx.x * 256 + threadIdx.x;
  if (e < E) epos[e] = atomicAdd(&cnt[dst[e]], 1);
}

// scan_a also produces dinv/dinv2 (folded dinv_k)
__global__ __launch_bounds__(512) void scan_a(const int* __restrict__ cnt,
                                              int* __restrict__ rs,
                                              int* __restrict__ bsum,
                                              float* __restrict__ dinv,
                                              float* __restrict__ dinv2, int n) {
  __shared__ int s[512];
  int tid = threadIdx.x;
  int gid = blockIdx.x * 512 + tid;
  int v = (gid < n) ? cnt[gid] : 0;
  if (gid < n) {
    float deg = 1.0f + (float)v;
    dinv[gid] = rsqrtf(deg);
    dinv2[gid] = __builtin_amdgcn_rcpf(deg);
  }
  s[tid] = v;
  __syncthreads();
  for (int off = 1; off < 512; off <<= 1) {
    int t = (tid >= off) ? s[tid - off] : 0;
    __syncthreads();
    s[tid] += t;
    __syncthreads();
  }
  if (gid < n) rs[gid] = s[tid] - v;
  if (tid == 511) bsum[blockIdx.x] = s[511];
}

// scan_b also computes per-graph boundaries (folded bounds_k)
__global__ __launch_bounds__(256) void scan_b(const int* __restrict__ bsum,
                                              int* __restrict__ boff, int nb,
                                              const int* __restrict__ batch,
                                              int* __restrict__ gstart, int n,
                                              int G) {
  __shared__ int s[256];
  int tid = threadIdx.x;
  int v = (tid < nb) ? bsum[tid] : 0;
  s[tid] = v;
  __syncthreads();
  for (int off = 1; off < 256; off <<= 1) {
    int t = (tid >= off) ? s[tid - off] : 0;
    __syncthreads();
    s[tid] += t;
    __syncthreads();
  }
  if (tid < nb) boff[tid] = s[tid] - v;
  if (tid <= G) {
    int lo = 0, hi = n;
    while (lo < hi) {
      int mid = (lo + hi) >> 1;
      if (batch[mid] < tid) lo = mid + 1;
      else hi = mid;
    }
    gstart[tid] = lo;
  }
}

__global__ __launch_bounds__(512) void scan_c(const int* __restrict__ boff,
                                              int* __restrict__ rs, int n, int E) {
  int gid = blockIdx.x * 512 + threadIdx.x;
  if (gid < n) rs[gid] += boff[blockIdx.x];
  if (gid == 0) rs[n] = E;
}

__global__ __launch_bounds__(256) void fill_k(const int* __restrict__ src,
                                              const int* __restrict__ dst,
                                              const int* __restrict__ rs,
                                              const int* __restrict__ epos,
                                              const float* __restrict__ dinv,
                                              int* __restrict__ col,
                                              float* __restrict__ normv, int E) {
  int e = blockIdx.x * 256 + threadIdx.x;
  if (e >= E) return;
  int s = src[e], d = dst[e];
  int pos = rs[d] + epos[e];
  col[pos] = s;
  normv[pos] = dinv[s] * dinv[d];
}

// ---------------- W -> transposed split-bf16 (all 4 layers) ----------------
// thread handles k-pair (2k,2k+1) of output row n

__global__ __launch_bounds__(256) void wconv_all(const float* __restrict__ W0,
                                                 const float* __restrict__ W1,
                                                 const float* __restrict__ W2,
                                                 const float* __restrict__ W3,
                                                 unsigned short* __restrict__ WtHi,
                                                 unsigned short* __restrict__ WtLo) {
  int l = blockIdx.y;
  const float* W = (l == 0) ? W0 : (l == 1) ? W1 : (l == 2) ? W2 : W3;
  int idx = blockIdx.x * 256 + threadIdx.x;
  if (idx >= 8192) return;
  int n = idx & 127, k = (idx >> 7) * 2;
  float w0 = W[k * 128 + n], w1 = W[(k + 1) * 128 + n];
  unsigned h01 = pk_bf16(w0, w1);
  float hf0 = __uint_as_float(h01 << 16);
  float hf1 = __uint_as_float(h01 & 0xFFFF0000u);
  unsigned l01 = pk_bf16(w0 - hf0, w1 - hf1);
  *(unsigned*)&WtHi[l * 16384 + n * 128 + k] = h01;
  *(unsigned*)&WtLo[l * 16384 + n * 128 + k] = l01;
}

// ---------------- MFMA GEMM: O[M,128](fp16) = A[M,128](f32) @ W ----------------

#define LDK 136

__global__ __launch_bounds__(256) void gemm_mfma(const float* __restrict__ A,
                                                 const unsigned short* __restrict__ WtHi,
                                                 const unsigned short* __restrict__ WtLo,
                                                 __half* __restrict__ O, int M) {
  __shared__ unsigned short sHi[128 * LDK];
  __shared__ unsigned short sLo[128 * LDK];
  int tid = threadIdx.x;
#pragma unroll
  for (int i = 0; i < 8; ++i) {
    int c = tid + i * 256;
    int n = c >> 4;
    int off = (c & 15) * 8;
    *(ushort8*)&sHi[n * LDK + off] = *(const ushort8*)&WtHi[c * 8];
    *(ushort8*)&sLo[n * LDK + off] = *(const ushort8*)&WtLo[c * 8];
  }
  __syncthreads();

  int wv = tid >> 6, lane = tid & 63;
  int r0 = blockIdx.x * 128 + wv * 32;
  int lrow = lane & 15, lk = (lane >> 4) * 8;

  f32x4 acc[2][8] = {};
#pragma unroll
  for (int kk = 0; kk < 4; ++kk) {
    int k0 = kk * 32 + lk;
    short8 ahi[2], alo[2];
#pragma unroll
    for (int fr = 0; fr < 2; ++fr) {
      int row = r0 + fr * 16 + lrow;
      row = row < M ? row : M - 1;
      const float* ap = &A[(size_t)row * 128 + k0];
      float4 a0 = *(const float4*)ap;
      float4 a1 = *(const float4*)(ap + 4);
      union { short8 v; unsigned u32[4]; } h_, l_;
#define SPLIT2(slot, x, y)                              \
      {                                                 \
        unsigned hh = pk_bf16((x), (y));                \
        h_.u32[slot] = hh;                              \
        float hf0 = __uint_as_float(hh << 16);          \
        float hf1 = __uint_as_float(hh & 0xFFFF0000u);  \
        l_.u32[slot] = pk_bf16((x) - hf0, (y) - hf1);   \
      }
      SPLIT2(0, a0.x, a0.y)
      SPLIT2(1, a0.z, a0.w)
      SPLIT2(2, a1.x, a1.y)
      SPLIT2(3, a1.z, a1.w)
#undef SPLIT2
      ahi[fr] = h_.v;
      alo[fr] = l_.v;
    }
#pragma unroll
    for (int c = 0; c < 8; ++c) {
      int bidx = (c * 16 + lrow) * LDK + k0;
      short8 bhi = *(const short8*)&sHi[bidx];
      short8 blo = *(const short8*)&sLo[bidx];
#pragma unroll
      for (int fr = 0; fr < 2; ++fr) {
        acc[fr][c] = __builtin_amdgcn_mfma_f32_16x16x32_bf16(ahi[fr], bhi, acc[fr][c], 0, 0, 0);
        acc[fr][c] = __builtin_amdgcn_mfma_f32_16x16x32_bf16(ahi[fr], blo, acc[fr][c], 0, 0, 0);
        acc[fr][c] = __builtin_amdgcn_mfma_f32_16x16x32_bf16(alo[fr], bhi, acc[fr][c], 0, 0, 0);
      }
    }
  }
#pragma unroll
  for (int fr = 0; fr < 2; ++fr) {
#pragma unroll
    for (int c = 0; c < 8; ++c) {
#pragma unroll
      for (int r = 0; r < 4; ++r) {
        int row = r0 + fr * 16 + (lane >> 4) * 4 + r;
        if (row < M)
          O[(size_t)row * 128 + c * 16 + (lane & 15)] = __float2half(acc[fr][c][r]);
      }
    }
  }
}

// ---------------- fused gather + self-loop + bias + tanh ----------------
// wave per node; 4 lane-groups of 16; group g loads edge slots g, g+4, ...;
// epilogue: group g finalizes features {2g, 2g+1} of its li-chunk (no
// redundant tanh), fast_tanh instead of libm tanhf.

__global__ __launch_bounds__(256) void gather_k(const __half* __restrict__ h,
                                                const int* __restrict__ rs,
                                                const int* __restrict__ col,
                                                const float* __restrict__ normv,
                                                const float* __restrict__ dinv2,
                                                const float* __restrict__ bias,
                                                float* __restrict__ out, int N) {
  int wid = (int)((blockIdx.x * (size_t)blockDim.x + threadIdx.x) >> 6);
  if (wid >= N) return;
  int lane = threadIdx.x & 63;
  int grp = lane >> 4;   // 0..3: edge slot
  int li = lane & 15;    // feature chunk: features [li*8, li*8+8)
  int s = rs[wid], e = rs[wid + 1];
  const h8* hrow = (const h8*)h;  // row i = hrow[i*16 + li]

  float ac[8] = {};
  int n16 = (e - s) >> 4;
  int base = s + grp;
  for (int it = 0; it < n16; ++it, base += 16) {
    int c0 = col[base], c1 = col[base + 4], c2 = col[base + 8], c3 = col[base + 12];
    float w0 = normv[base], w1 = normv[base + 4], w2 = normv[base + 8],
          w3 = normv[base + 12];
    h8 v0 = hrow[(size_t)c0 * 16 + li];
    h8 v1 = hrow[(size_t)c1 * 16 + li];
    h8 v2 = hrow[(size_t)c2 * 16 + li];
    h8 v3 = hrow[(size_t)c3 * 16 + li];
#define ACC(V, W)                                    \
    {                                                \
      float2 f0 = __half22float2((V).a);             \
      float2 f1 = __half22float2((V).b);             \
      float2 f2 = __half22float2((V).c);             \
      float2 f3 = __half22float2((V).d);             \
      ac[0] += (W) * f0.x; ac[1] += (W) * f0.y;      \
      ac[2] += (W) * f1.x; ac[3] += (W) * f1.y;      \
      ac[4] += (W) * f2.x; ac[5] += (W) * f2.y;      \
      ac[6] += (W) * f3.x; ac[7] += (W) * f3.y;      \
    }
    ACC(v0, w0) ACC(v1, w1) ACC(v2, w2) ACC(v3, w3)
  }
  for (int idx = base; idx < e; idx += 4) {
    int c = col[idx];
    float w = normv[idx];
    h8 v = hrow[(size_t)c * 16 + li];
    ACC(v, w)
  }
#undef ACC
  // combine the 4 edge-slots: full sums in all lanes
#pragma unroll
  for (int j = 0; j < 8; ++j) {
    ac[j] += __shfl_xor(ac[j], 16);
    ac[j] += __shfl_xor(ac[j], 32);
  }

  // group g finalizes features {2g, 2g+1} (constant-index selects only)
  float a0 = grp == 0 ? ac[0] : grp == 1 ? ac[2] : grp == 2 ? ac[4] : ac[6];
  float a1 = grp == 0 ? ac[1] : grp == 1 ? ac[3] : grp == 2 ? ac[5] : ac[7];

  float d2 = dinv2[wid];
  h8 sv = hrow[(size_t)wid * 16 + li];
  __half2 svh = grp == 0 ? sv.a : grp == 1 ? sv.b : grp == 2 ? sv.c : sv.d;
  float2 sj = __half22float2(svh);
  float2 bj = *(const float2*)&bias[li * 8 + 2 * grp];
  float o0 = fast_tanh(a0 + sj.x * d2 + bj.x);
  float o1 = fast_tanh(a1 + sj.y * d2 + bj.y);
  *(float2*)&out[(size_t)wid * 128 + li * 8 + 2 * grp] = make_float2(o0, o1);
}

// ---------------- pooling ----------------

#define CH 16

__global__ __launch_bounds__(128) void pool_partial(const float* __restrict__ h,
                                                    const int* __restrict__ gstart,
                                                    float* __restrict__ pmax,
                                                    float* __restrict__ psum) {
  int g = blockIdx.x, c = blockIdx.y, f = threadIdx.x;
  int s = gstart[g], e = gstart[g + 1];
  long long len = e - s;
  int cs = s + (int)(len * c / CH);
  int ce = s + (int)(len * (c + 1) / CH);
  float m = -INFINITY, sum = 0.f;
  for (int n = cs; n < ce; ++n) {
    float v = h[(size_t)n * 128 + f];
    m = fmaxf(m, v);
    sum += v;
  }
  pmax[((size_t)g * CH + c) * 128 + f] = m;
  psum[((size_t)g * CH + c) * 128 + f] = sum;
}

// pool finalize + output head (merged)
__global__ __launch_bounds__(128) void pool_head(const float* __restrict__ pmax,
                                                 const float* __restrict__ psum,
                                                 const int* __restrict__ gstart,
                                                 const float* __restrict__ Wout,
                                                 const float* __restrict__ bout,
                                                 float* __restrict__ out, int G) {
  __shared__ float pl[256];
  int g = blockIdx.x, f = threadIdx.x;
  float m = -INFINITY, s = 0.f;
  for (int c = 0; c < CH; ++c) {
    m = fmaxf(m, pmax[((size_t)g * CH + c) * 128 + f]);
    s += psum[((size_t)g * CH + c) * 128 + f];
  }
  int cnt = gstart[g + 1] - gstart[g];
  float mean = s / fmaxf((float)cnt, 1.0f);
  float* pooled = out + (size_t)G * 10;
  pooled[(size_t)g * 256 + f] = m;
  pooled[(size_t)g * 256 + 128 + f] = mean;
  pl[f] = m;
  pl[128 + f] = mean;
  __syncthreads();
  if (f < 10) {
    float acc = bout[f];
    for (int k = 0; k < 256; ++k) acc += pl[k] * Wout[k * 10 + f];
    out[(size_t)g * 10 + f] = acc;
  }
}

// ---------------- launch ----------------

extern "C" void kernel_launch(void* const* d_in, const int* in_sizes, int n_in,
                              void* d_out, int out_size, void* d_ws, size_t ws_size,
                              hipStream_t stream) {
  const float* x = (const float*)d_in[0];
  const int* ei = (const int*)d_in[1];
  const int* batch = (const int*)d_in[2];
  const float* W[4] = {(const float*)d_in[3], (const float*)d_in[5],
                       (const float*)d_in[7], (const float*)d_in[9]};
  const float* Bz[4] = {(const float*)d_in[4], (const float*)d_in[6],
                        (const float*)d_in[8], (const float*)d_in[10]};
  const float* Wout = (const float*)d_in[11];
  const float* bout = (const float*)d_in[12];
  const int N = in_sizes[0] / 128;
  const int E = in_sizes[1] / 2;
  const int G = 64;
  const int* srcp = ei;
  const int* dstp = ei + E;
  float* out = (float*)d_out;

  char* wsb = (char*)d_ws;
  size_t off = 0;
  auto alloc = [&](size_t bytes) -> void* {
    void* p = wsb + off;
    off = (off + bytes + 255) & ~(size_t)255;
    return p;
  };
  __half* bufA = (__half*)alloc((size_t)N * 128 * 2);   // fp16 GEMM output
  float* bufB = (float*)alloc((size_t)N * 128 * 4);     // f32 gather output
  int* cnt = (int*)alloc((size_t)N * 4);
  int* epos = (int*)alloc((size_t)E * 4);
  float* dinv = (float*)alloc((size_t)N * 4);
  float* dinv2 = (float*)alloc((size_t)N * 4);
  int* rs = (int*)alloc((size_t)(N + 1) * 4);
  int* col = (int*)alloc((size_t)E * 4);
  float* normv = (float*)alloc((size_t)E * 4);
  int* bsum = (int*)alloc(4096);
  int* boff = (int*)alloc(4096);
  int* gstart = (int*)alloc(4096);
  float* pmax = (float*)alloc((size_t)G * CH * 128 * 4);
  float* psum = (float*)alloc((size_t)G * CH * 128 * 4);
  unsigned short* WtHi = (unsigned short*)alloc(4 * 16384 * 2);
  unsigned short* WtLo = (unsigned short*)alloc(4 * 16384 * 2);
  if (off > ws_size) return;

  hipMemsetAsync(cnt, 0, (size_t)N * 4, stream);

  count_k<<<(E + 255) / 256, 256, 0, stream>>>(dstp, cnt, epos, E);
  int nsb = (N + 511) / 512;
  scan_a<<<nsb, 512, 0, stream>>>(cnt, rs, bsum, dinv, dinv2, N);
  scan_b<<<1, 256, 0, stream>>>(bsum, boff, nsb, batch, gstart, N, G);
  scan_c<<<nsb, 512, 0, stream>>>(boff, rs, N, E);
  fill_k<<<(E + 255) / 256, 256, 0, stream>>>(srcp, dstp, rs, epos, dinv, col,
                                              normv, E);
  wconv_all<<<dim3(32, 4), 256, 0, stream>>>(W[0], W[1], W[2], W[3], WtHi, WtLo);

  const float* in = x;
  for (int l = 0; l < 4; ++l) {
    gemm_mfma<<<(N + 127) / 128, 256, 0, stream>>>(in, WtHi + l * 16384,
                                                   WtLo + l * 16384, bufA, N);
    gather_k<<<((size_t)N * 64 + 255) / 256, 256, 0, stream>>>(bufA, rs, col, normv,
                                                               dinv2, Bz[l], bufB, N);
    in = bufB;
  }

  pool_partial<<<dim3(G, CH), 128, 0, stream>>>(bufB, gstart, pmax, psum);
  pool_head<<<G, 128, 0, stream>>>(pmax, psum, gstart, Wout, bout, out, G);
}

// Round 6
// 537.189 us; speedup vs baseline: 2.2378x; 1.0076x over previous
//
#include <hip/hip_runtime.h>
#include <hip/hip_fp16.h>
#include <cmath>

typedef __attribute__((ext_vector_type(8))) short short8;
typedef __attribute__((ext_vector_type(8))) unsigned short ushort8;
typedef __attribute__((ext_vector_type(4))) float f32x4;

struct h8 { __half2 a, b, c, d; };  // 16B = 8 fp16 features

__device__ __forceinline__ unsigned pk_bf16(float a, float b) {
  unsigned r;
  asm("v_cvt_pk_bf16_f32 %0, %1, %2" : "=v"(r) : "v"(a), "v"(b));
  return r;  // lo16 = bf16(a), hi16 = bf16(b), RNE
}

__device__ __forceinline__ float fast_tanh(float x) {
  float e2 = __expf(2.0f * x);
  return 1.0f - 2.0f * __builtin_amdgcn_rcpf(e2 + 1.0f);
}

// ---------------- CSR build ----------------

__global__ __launch_bounds__(256) void count_k(const int* __restrict__ dst,
                                               int* __restrict__ cnt,
                                               int* __restrict__ epos, int E) {
  int e = blockIdx.x * 256 + threadIdx.x;
  if (e < E) epos[e] = atomicAdd(&cnt[dst[e]], 1);
}

__global__ __launch_bounds__(512) void scan_a(const int* __restrict__ cnt,
                                              int* __restrict__ rs,
                                              int* __restrict__ bsum,
                                              float* __restrict__ dinv,
                                              float* __restrict__ dinv2, int n) {
  __shared__ int s[512];
  int tid = threadIdx.x;
  int gid = blockIdx.x * 512 + tid;
  int v = (gid < n) ? cnt[gid] : 0;
  if (gid < n) {
    float deg = 1.0f + (float)v;
    dinv[gid] = rsqrtf(deg);
    dinv2[gid] = __builtin_amdgcn_rcpf(deg);
  }
  s[tid] = v;
  __syncthreads();
  for (int off = 1; off < 512; off <<= 1) {
    int t = (tid >= off) ? s[tid - off] : 0;
    __syncthreads();
    s[tid] += t;
    __syncthreads();
  }
  if (gid < n) rs[gid] = s[tid] - v;
  if (tid == 511) bsum[blockIdx.x] = s[511];
}

__global__ __launch_bounds__(256) void scan_b(const int* __restrict__ bsum,
                                              int* __restrict__ boff, int nb,
                                              const int* __restrict__ batch,
                                              int* __restrict__ gstart, int n,
                                              int G) {
  __shared__ int s[256];
  int tid = threadIdx.x;
  int v = (tid < nb) ? bsum[tid] : 0;
  s[tid] = v;
  __syncthreads();
  for (int off = 1; off < 256; off <<= 1) {
    int t = (tid >= off) ? s[tid - off] : 0;
    __syncthreads();
    s[tid] += t;
    __syncthreads();
  }
  if (tid < nb) boff[tid] = s[tid] - v;
  if (tid <= G) {
    int lo = 0, hi = n;
    while (lo < hi) {
      int mid = (lo + hi) >> 1;
      if (batch[mid] < tid) lo = mid + 1;
      else hi = mid;
    }
    gstart[tid] = lo;
  }
}

__global__ __launch_bounds__(512) void scan_c(const int* __restrict__ boff,
                                              int* __restrict__ rs, int n, int E) {
  int gid = blockIdx.x * 512 + threadIdx.x;
  if (gid < n) rs[gid] += boff[blockIdx.x];
  if (gid == 0) rs[n] = E;
}

// packed edge payload: one 8B scattered store per edge
__global__ __launch_bounds__(256) void fill_k(const int* __restrict__ src,
                                              const int* __restrict__ dst,
                                              const int* __restrict__ rs,
                                              const int* __restrict__ epos,
                                              const float* __restrict__ dinv,
                                              int2* __restrict__ edata, int E) {
  int e = blockIdx.x * 256 + threadIdx.x;
  if (e >= E) return;
  int s = src[e], d = dst[e];
  int pos = rs[d] + epos[e];
  int2 ed;
  ed.x = s;
  ed.y = __float_as_int(dinv[s] * dinv[d]);
  edata[pos] = ed;
}

// ---------------- W -> transposed split-bf16 (all 4 layers) ----------------

__global__ __launch_bounds__(256) void wconv_all(const float* __restrict__ W0,
                                                 const float* __restrict__ W1,
                                                 const float* __restrict__ W2,
                                                 const float* __restrict__ W3,
                                                 unsigned short* __restrict__ WtHi,
                                                 unsigned short* __restrict__ WtLo) {
  int l = blockIdx.y;
  const float* W = (l == 0) ? W0 : (l == 1) ? W1 : (l == 2) ? W2 : W3;
  int idx = blockIdx.x * 256 + threadIdx.x;
  if (idx >= 8192) return;
  int n = idx & 127, k = (idx >> 7) * 2;
  float w0 = W[k * 128 + n], w1 = W[(k + 1) * 128 + n];
  unsigned h01 = pk_bf16(w0, w1);
  float hf0 = __uint_as_float(h01 << 16);
  float hf1 = __uint_as_float(h01 & 0xFFFF0000u);
  unsigned l01 = pk_bf16(w0 - hf0, w1 - hf1);
  *(unsigned*)&WtHi[l * 16384 + n * 128 + k] = h01;
  *(unsigned*)&WtLo[l * 16384 + n * 128 + k] = l01;
}

// ---------------- shared GEMM core pieces ----------------

#define LDK 136

// layer-0 GEMM: A is f32, split in-register
__global__ __launch_bounds__(256) void gemm_mfma(const float* __restrict__ A,
                                                 const unsigned short* __restrict__ WtHi,
                                                 const unsigned short* __restrict__ WtLo,
                                                 __half* __restrict__ O, int M) {
  __shared__ unsigned short sHi[128 * LDK];
  __shared__ unsigned short sLo[128 * LDK];
  int tid = threadIdx.x;
#pragma unroll
  for (int i = 0; i < 8; ++i) {
    int c = tid + i * 256;
    int n = c >> 4;
    int off = (c & 15) * 8;
    *(ushort8*)&sHi[n * LDK + off] = *(const ushort8*)&WtHi[c * 8];
    *(ushort8*)&sLo[n * LDK + off] = *(const ushort8*)&WtLo[c * 8];
  }
  __syncthreads();

  int wv = tid >> 6, lane = tid & 63;
  int r0 = blockIdx.x * 128 + wv * 32;
  int lrow = lane & 15, lk = (lane >> 4) * 8;

  f32x4 acc[2][8] = {};
#pragma unroll
  for (int kk = 0; kk < 4; ++kk) {
    int k0 = kk * 32 + lk;
    short8 ahi[2], alo[2];
#pragma unroll
    for (int fr = 0; fr < 2; ++fr) {
      int row = r0 + fr * 16 + lrow;
      row = row < M ? row : M - 1;
      const float* ap = &A[(size_t)row * 128 + k0];
      float4 a0 = *(const float4*)ap;
      float4 a1 = *(const float4*)(ap + 4);
      union { short8 v; unsigned u32[4]; } h_, l_;
#define SPLIT2(slot, x, y)                              \
      {                                                 \
        unsigned hh = pk_bf16((x), (y));                \
        h_.u32[slot] = hh;                              \
        float hf0 = __uint_as_float(hh << 16);          \
        float hf1 = __uint_as_float(hh & 0xFFFF0000u);  \
        l_.u32[slot] = pk_bf16((x) - hf0, (y) - hf1);   \
      }
      SPLIT2(0, a0.x, a0.y)
      SPLIT2(1, a0.z, a0.w)
      SPLIT2(2, a1.x, a1.y)
      SPLIT2(3, a1.z, a1.w)
#undef SPLIT2
      ahi[fr] = h_.v;
      alo[fr] = l_.v;
    }
#pragma unroll
    for (int c = 0; c < 8; ++c) {
      int bidx = (c * 16 + lrow) * LDK + k0;
      short8 bhi = *(const short8*)&sHi[bidx];
      short8 blo = *(const short8*)&sLo[bidx];
#pragma unroll
      for (int fr = 0; fr < 2; ++fr) {
        acc[fr][c] = __builtin_amdgcn_mfma_f32_16x16x32_bf16(ahi[fr], bhi, acc[fr][c], 0, 0, 0);
        acc[fr][c] = __builtin_amdgcn_mfma_f32_16x16x32_bf16(ahi[fr], blo, acc[fr][c], 0, 0, 0);
        acc[fr][c] = __builtin_amdgcn_mfma_f32_16x16x32_bf16(alo[fr], bhi, acc[fr][c], 0, 0, 0);
      }
    }
  }
#pragma unroll
  for (int fr = 0; fr < 2; ++fr) {
#pragma unroll
    for (int c = 0; c < 8; ++c) {
#pragma unroll
      for (int r = 0; r < 4; ++r) {
        int row = r0 + fr * 16 + (lane >> 4) * 4 + r;
        if (row < M)
          O[(size_t)row * 128 + c * 16 + (lane & 15)] = __float2half(acc[fr][c][r]);
      }
    }
  }
}

// layers 1-3 GEMM: A pre-split as bf16 hi/lo arrays -> pure load + MFMA
__global__ __launch_bounds__(256) void gemm_fast(const unsigned short* __restrict__ AHi,
                                                 const unsigned short* __restrict__ ALo,
                                                 const unsigned short* __restrict__ WtHi,
                                                 const unsigned short* __restrict__ WtLo,
                                                 __half* __restrict__ O, int M) {
  __shared__ unsigned short sHi[128 * LDK];
  __shared__ unsigned short sLo[128 * LDK];
  int tid = threadIdx.x;
#pragma unroll
  for (int i = 0; i < 8; ++i) {
    int c = tid + i * 256;
    int n = c >> 4;
    int off = (c & 15) * 8;
    *(ushort8*)&sHi[n * LDK + off] = *(const ushort8*)&WtHi[c * 8];
    *(ushort8*)&sLo[n * LDK + off] = *(const ushort8*)&WtLo[c * 8];
  }
  __syncthreads();

  int wv = tid >> 6, lane = tid & 63;
  int r0 = blockIdx.x * 128 + wv * 32;
  int lrow = lane & 15, lk = (lane >> 4) * 8;

  f32x4 acc[2][8] = {};
#pragma unroll
  for (int kk = 0; kk < 4; ++kk) {
    int k0 = kk * 32 + lk;
    short8 ahi[2], alo[2];
#pragma unroll
    for (int fr = 0; fr < 2; ++fr) {
      int row = r0 + fr * 16 + lrow;
      row = row < M ? row : M - 1;
      ahi[fr] = *(const short8*)&AHi[(size_t)row * 128 + k0];
      alo[fr] = *(const short8*)&ALo[(size_t)row * 128 + k0];
    }
#pragma unroll
    for (int c = 0; c < 8; ++c) {
      int bidx = (c * 16 + lrow) * LDK + k0;
      short8 bhi = *(const short8*)&sHi[bidx];
      short8 blo = *(const short8*)&sLo[bidx];
#pragma unroll
      for (int fr = 0; fr < 2; ++fr) {
        acc[fr][c] = __builtin_amdgcn_mfma_f32_16x16x32_bf16(ahi[fr], bhi, acc[fr][c], 0, 0, 0);
        acc[fr][c] = __builtin_amdgcn_mfma_f32_16x16x32_bf16(ahi[fr], blo, acc[fr][c], 0, 0, 0);
        acc[fr][c] = __builtin_amdgcn_mfma_f32_16x16x32_bf16(alo[fr], bhi, acc[fr][c], 0, 0, 0);
      }
    }
  }
#pragma unroll
  for (int fr = 0; fr < 2; ++fr) {
#pragma unroll
    for (int c = 0; c < 8; ++c) {
#pragma unroll
      for (int r = 0; r < 4; ++r) {
        int row = r0 + fr * 16 + (lane >> 4) * 4 + r;
        if (row < M)
          O[(size_t)row * 128 + c * 16 + (lane & 15)] = __float2half(acc[fr][c][r]);
      }
    }
  }
}

// ---------------- fused gather + self-loop + bias + tanh ----------------
// writes split-bf16 hi/lo pair (consumed by gemm_fast / pooling)

__global__ __launch_bounds__(256) void gather_k(const __half* __restrict__ h,
                                                const int* __restrict__ rs,
                                                const int2* __restrict__ edata,
                                                const float* __restrict__ dinv2,
                                                const float* __restrict__ bias,
                                                unsigned* __restrict__ OHi,
                                                unsigned* __restrict__ OLo, int N) {
  int wid = (int)((blockIdx.x * (size_t)blockDim.x + threadIdx.x) >> 6);
  if (wid >= N) return;
  int lane = threadIdx.x & 63;
  int grp = lane >> 4;   // 0..3: edge slot
  int li = lane & 15;    // feature chunk: features [li*8, li*8+8)
  int s = rs[wid], e = rs[wid + 1];
  const h8* hrow = (const h8*)h;

  float ac[8] = {};
  int n16 = (e - s) >> 4;
  int base = s + grp;
  for (int it = 0; it < n16; ++it, base += 16) {
    int2 e0 = edata[base], e1 = edata[base + 4], e2 = edata[base + 8],
         e3 = edata[base + 12];
    float w0 = __int_as_float(e0.y), w1 = __int_as_float(e1.y),
          w2 = __int_as_float(e2.y), w3 = __int_as_float(e3.y);
    h8 v0 = hrow[(size_t)e0.x * 16 + li];
    h8 v1 = hrow[(size_t)e1.x * 16 + li];
    h8 v2 = hrow[(size_t)e2.x * 16 + li];
    h8 v3 = hrow[(size_t)e3.x * 16 + li];
#define ACC(V, W)                                    \
    {                                                \
      float2 f0 = __half22float2((V).a);             \
      float2 f1 = __half22float2((V).b);             \
      float2 f2 = __half22float2((V).c);             \
      float2 f3 = __half22float2((V).d);             \
      ac[0] += (W) * f0.x; ac[1] += (W) * f0.y;      \
      ac[2] += (W) * f1.x; ac[3] += (W) * f1.y;      \
      ac[4] += (W) * f2.x; ac[5] += (W) * f2.y;      \
      ac[6] += (W) * f3.x; ac[7] += (W) * f3.y;      \
    }
    ACC(v0, w0) ACC(v1, w1) ACC(v2, w2) ACC(v3, w3)
  }
  for (int idx = base; idx < e; idx += 4) {
    int2 ed = edata[idx];
    float w = __int_as_float(ed.y);
    h8 v = hrow[(size_t)ed.x * 16 + li];
    ACC(v, w)
  }
#undef ACC
#pragma unroll
  for (int j = 0; j < 8; ++j) {
    ac[j] += __shfl_xor(ac[j], 16);
    ac[j] += __shfl_xor(ac[j], 32);
  }

  float a0 = grp == 0 ? ac[0] : grp == 1 ? ac[2] : grp == 2 ? ac[4] : ac[6];
  float a1 = grp == 0 ? ac[1] : grp == 1 ? ac[3] : grp == 2 ? ac[5] : ac[7];

  float d2 = dinv2[wid];
  h8 sv = hrow[(size_t)wid * 16 + li];
  __half2 svh = grp == 0 ? sv.a : grp == 1 ? sv.b : grp == 2 ? sv.c : sv.d;
  float2 sj = __half22float2(svh);
  float2 bj = *(const float2*)&bias[li * 8 + 2 * grp];
  float o0 = fast_tanh(a0 + sj.x * d2 + bj.x);
  float o1 = fast_tanh(a1 + sj.y * d2 + bj.y);

  unsigned hp = pk_bf16(o0, o1);
  float r0f = __uint_as_float(hp << 16);
  float r1f = __uint_as_float(hp & 0xFFFF0000u);
  unsigned lp = pk_bf16(o0 - r0f, o1 - r1f);
  unsigned idx = (unsigned)wid * 64 + li * 4 + grp;
  OHi[idx] = hp;
  OLo[idx] = lp;
}

// ---------------- pooling ----------------

#define CH 16

__global__ __launch_bounds__(128) void pool_partial(const unsigned short* __restrict__ Hi,
                                                    const unsigned short* __restrict__ Lo,
                                                    const int* __restrict__ gstart,
                                                    float* __restrict__ pmax,
                                                    float* __restrict__ psum) {
  int g = blockIdx.x, c = blockIdx.y, f = threadIdx.x;
  int s = gstart[g], e = gstart[g + 1];
  long long len = e - s;
  int cs = s + (int)(len * c / CH);
  int ce = s + (int)(len * (c + 1) / CH);
  float m = -INFINITY, sum = 0.f;
  for (int n = cs; n < ce; ++n) {
    unsigned hv = Hi[(size_t)n * 128 + f];
    unsigned lv = Lo[(size_t)n * 128 + f];
    float v = __uint_as_float(hv << 16) + __uint_as_float(lv << 16);
    m = fmaxf(m, v);
    sum += v;
  }
  pmax[((size_t)g * CH + c) * 128 + f] = m;
  psum[((size_t)g * CH + c) * 128 + f] = sum;
}

__global__ __launch_bounds__(128) void pool_head(const float* __restrict__ pmax,
                                                 const float* __restrict__ psum,
                                                 const int* __restrict__ gstart,
                                                 const float* __restrict__ Wout,
                                                 const float* __restrict__ bout,
                                                 float* __restrict__ out, int G) {
  __shared__ float pl[256];
  int g = blockIdx.x, f = threadIdx.x;
  float m = -INFINITY, s = 0.f;
  for (int c = 0; c < CH; ++c) {
    m = fmaxf(m, pmax[((size_t)g * CH + c) * 128 + f]);
    s += psum[((size_t)g * CH + c) * 128 + f];
  }
  int cnt = gstart[g + 1] - gstart[g];
  float mean = s / fmaxf((float)cnt, 1.0f);
  float* pooled = out + (size_t)G * 10;
  pooled[(size_t)g * 256 + f] = m;
  pooled[(size_t)g * 256 + 128 + f] = mean;
  pl[f] = m;
  pl[128 + f] = mean;
  __syncthreads();
  if (f < 10) {
    float acc = bout[f];
    for (int k = 0; k < 256; ++k) acc += pl[k] * Wout[k * 10 + f];
    out[(size_t)g * 10 + f] = acc;
  }
}

// ---------------- launch ----------------

extern "C" void kernel_launch(void* const* d_in, const int* in_sizes, int n_in,
                              void* d_out, int out_size, void* d_ws, size_t ws_size,
                              hipStream_t stream) {
  const float* x = (const float*)d_in[0];
  const int* ei = (const int*)d_in[1];
  const int* batch = (const int*)d_in[2];
  const float* W[4] = {(const float*)d_in[3], (const float*)d_in[5],
                       (const float*)d_in[7], (const float*)d_in[9]};
  const float* Bz[4] = {(const float*)d_in[4], (const float*)d_in[6],
                        (const float*)d_in[8], (const float*)d_in[10]};
  const float* Wout = (const float*)d_in[11];
  const float* bout = (const float*)d_in[12];
  const int N = in_sizes[0] / 128;
  const int E = in_sizes[1] / 2;
  const int G = 64;
  const int* srcp = ei;
  const int* dstp = ei + E;
  float* out = (float*)d_out;

  char* wsb = (char*)d_ws;
  size_t off = 0;
  auto alloc = [&](size_t bytes) -> void* {
    void* p = wsb + off;
    off = (off + bytes + 255) & ~(size_t)255;
    return p;
  };
  __half* bufA = (__half*)alloc((size_t)N * 128 * 2);      // fp16 GEMM output
  unsigned* OHi = (unsigned*)alloc((size_t)N * 64 * 4);    // bf16-hi pairs
  unsigned* OLo = (unsigned*)alloc((size_t)N * 64 * 4);    // bf16-lo pairs
  int* cnt = (int*)alloc((size_t)N * 4);
  int* epos = (int*)alloc((size_t)E * 4);
  float* dinv = (float*)alloc((size_t)N * 4);
  float* dinv2 = (float*)alloc((size_t)N * 4);
  int* rs = (int*)alloc((size_t)(N + 1) * 4);
  int2* edata = (int2*)alloc((size_t)E * 8);
  int* bsum = (int*)alloc(4096);
  int* boff = (int*)alloc(4096);
  int* gstart = (int*)alloc(4096);
  float* pmax = (float*)alloc((size_t)G * CH * 128 * 4);
  float* psum = (float*)alloc((size_t)G * CH * 128 * 4);
  unsigned short* WtHi = (unsigned short*)alloc(4 * 16384 * 2);
  unsigned short* WtLo = (unsigned short*)alloc(4 * 16384 * 2);
  if (off > ws_size) return;

  hipMemsetAsync(cnt, 0, (size_t)N * 4, stream);

  count_k<<<(E + 255) / 256, 256, 0, stream>>>(dstp, cnt, epos, E);
  int nsb = (N + 511) / 512;
  scan_a<<<nsb, 512, 0, stream>>>(cnt, rs, bsum, dinv, dinv2, N);
  scan_b<<<1, 256, 0, stream>>>(bsum, boff, nsb, batch, gstart, N, G);
  scan_c<<<nsb, 512, 0, stream>>>(boff, rs, N, E);
  fill_k<<<(E + 255) / 256, 256, 0, stream>>>(srcp, dstp, rs, epos, dinv, edata, E);
  wconv_all<<<dim3(32, 4), 256, 0, stream>>>(W[0], W[1], W[2], W[3], WtHi, WtLo);

  for (int l = 0; l < 4; ++l) {
    if (l == 0)
      gemm_mfma<<<(N + 127) / 128, 256, 0, stream>>>(x, WtHi, WtLo, bufA, N);
    else
      gemm_fast<<<(N + 127) / 128, 256, 0, stream>>>((const unsigned short*)OHi,
                                                     (const unsigned short*)OLo,
                                                     WtHi + l * 16384,
                                                     WtLo + l * 16384, bufA, N);
    gather_k<<<((size_t)N * 64 + 255) / 256, 256, 0, stream>>>(bufA, rs, edata,
                                                               dinv2, Bz[l], OHi,
                                                               OLo, N);
  }

  pool_partial<<<dim3(G, CH), 128, 0, stream>>>((const unsigned short*)OHi,
                                                (const unsigned short*)OLo, gstart,
                                                pmax, psum);
  pool_head<<<G, 128, 0, stream>>>(pmax, psum, gstart, Wout, bout, out, G);
}

// Round 7
// 526.607 us; speedup vs baseline: 2.2828x; 1.0201x over previous
//
#include <hip/hip_runtime.h>
#include <hip/hip_fp16.h>
#include <cmath>

typedef __attribute__((ext_vector_type(8))) short short8;
typedef __attribute__((ext_vector_type(8))) unsigned short ushort8;
typedef __attribute__((ext_vector_type(8))) _Float16 f16x8;
typedef __attribute__((ext_vector_type(4))) float f32x4;

__device__ __forceinline__ unsigned pk_bf16(float a, float b) {
  unsigned r;
  asm("v_cvt_pk_bf16_f32 %0, %1, %2" : "=v"(r) : "v"(a), "v"(b));
  return r;  // lo16 = bf16(a), hi16 = bf16(b), RNE
}

__device__ __forceinline__ float fast_tanh(float x) {
  float e2 = __expf(2.0f * x);
  return 1.0f - 2.0f * __builtin_amdgcn_rcpf(e2 + 1.0f);
}

// f32 acc += (f16 lo/hi half of u32) * w  -- single VOP3P instruction
#define FM_LO(A, U, W) \
  asm("v_fma_mix_f32 %0, %1, %2, %0 op_sel_hi:[1,0,0]" : "+v"(A) : "v"(U), "v"(W))
#define FM_HI(A, U, W) \
  asm("v_fma_mix_f32 %0, %1, %2, %0 op_sel:[1,0,0] op_sel_hi:[1,0,0]" : "+v"(A) : "v"(U), "v"(W))

// ---------------- CSR build ----------------

__global__ __launch_bounds__(256) void count_k(const int* __restrict__ dst,
                                               int* __restrict__ cnt,
                                               int* __restrict__ epos, int E) {
  int e = blockIdx.x * 256 + threadIdx.x;
  if (e < E) epos[e] = atomicAdd(&cnt[dst[e]], 1);
}

__global__ __launch_bounds__(512) void scan_a(const int* __restrict__ cnt,
                                              int* __restrict__ rs,
                                              int* __restrict__ bsum,
                                              float* __restrict__ dinv,
                                              float* __restrict__ dinv2, int n) {
  __shared__ int s[512];
  int tid = threadIdx.x;
  int gid = blockIdx.x * 512 + tid;
  int v = (gid < n) ? cnt[gid] : 0;
  if (gid < n) {
    float deg = 1.0f + (float)v;
    dinv[gid] = rsqrtf(deg);
    dinv2[gid] = __builtin_amdgcn_rcpf(deg);
  }
  s[tid] = v;
  __syncthreads();
  for (int off = 1; off < 512; off <<= 1) {
    int t = (tid >= off) ? s[tid - off] : 0;
    __syncthreads();
    s[tid] += t;
    __syncthreads();
  }
  if (gid < n) rs[gid] = s[tid] - v;
  if (tid == 511) bsum[blockIdx.x] = s[511];
}

__global__ __launch_bounds__(256) void scan_b(const int* __restrict__ bsum,
                                              int* __restrict__ boff, int nb,
                                              const int* __restrict__ batch,
                                              int* __restrict__ gstart, int n,
                                              int G) {
  __shared__ int s[256];
  int tid = threadIdx.x;
  int v = (tid < nb) ? bsum[tid] : 0;
  s[tid] = v;
  __syncthreads();
  for (int off = 1; off < 256; off <<= 1) {
    int t = (tid >= off) ? s[tid - off] : 0;
    __syncthreads();
    s[tid] += t;
    __syncthreads();
  }
  if (tid < nb) boff[tid] = s[tid] - v;
  if (tid <= G) {
    int lo = 0, hi = n;
    while (lo < hi) {
      int mid = (lo + hi) >> 1;
      if (batch[mid] < tid) lo = mid + 1;
      else hi = mid;
    }
    gstart[tid] = lo;
  }
}

__global__ __launch_bounds__(512) void scan_c(const int* __restrict__ boff,
                                              int* __restrict__ rs, int n, int E) {
  int gid = blockIdx.x * 512 + threadIdx.x;
  if (gid < n) rs[gid] += boff[blockIdx.x];
  if (gid == 0) rs[n] = E;
}

__global__ __launch_bounds__(256) void fill_k(const int* __restrict__ src,
                                              const int* __restrict__ dst,
                                              const int* __restrict__ rs,
                                              const int* __restrict__ epos,
                                              const float* __restrict__ dinv,
                                              int2* __restrict__ edata, int E) {
  int e = blockIdx.x * 256 + threadIdx.x;
  if (e >= E) return;
  int s = src[e], d = dst[e];
  int pos = rs[d] + epos[e];
  int2 ed;
  ed.x = s;
  ed.y = __float_as_int(dinv[s] * dinv[d]);
  edata[pos] = ed;
}

// ---------------- W prep ----------------
// layer 0: transposed split-bf16 (for f32-input GEMM)
// layers 1-3: transposed split-fp16, lo pre-scaled by 1024

__global__ __launch_bounds__(256) void wconv_all(const float* __restrict__ W0,
                                                 const float* __restrict__ W1,
                                                 const float* __restrict__ W2,
                                                 const float* __restrict__ W3,
                                                 unsigned short* __restrict__ Wt0Hi,
                                                 unsigned short* __restrict__ Wt0Lo,
                                                 unsigned short* __restrict__ WfHi,
                                                 unsigned short* __restrict__ WfLo) {
  int l = blockIdx.y;
  const float* W = (l == 0) ? W0 : (l == 1) ? W1 : (l == 2) ? W2 : W3;
  int idx = blockIdx.x * 256 + threadIdx.x;
  if (idx >= 8192) return;
  int n = idx & 127, k = (idx >> 7) * 2;
  float w0 = W[k * 128 + n], w1 = W[(k + 1) * 128 + n];
  if (l == 0) {
    unsigned h01 = pk_bf16(w0, w1);
    float hf0 = __uint_as_float(h01 << 16);
    float hf1 = __uint_as_float(h01 & 0xFFFF0000u);
    unsigned l01 = pk_bf16(w0 - hf0, w1 - hf1);
    *(unsigned*)&Wt0Hi[n * 128 + k] = h01;
    *(unsigned*)&Wt0Lo[n * 128 + k] = l01;
  } else {
    __half2 hh = __float22half2_rn(make_float2(w0, w1));
    float r0 = __low2float(hh), r1 = __high2float(hh);
    __half2 ll = __float22half2_rn(make_float2((w0 - r0) * 1024.0f,
                                               (w1 - r1) * 1024.0f));
    *(__half2*)&WfHi[(l - 1) * 16384 + n * 128 + k] = hh;
    *(__half2*)&WfLo[(l - 1) * 16384 + n * 128 + k] = ll;
  }
}

// ---------------- layer-0 GEMM: f32 A, split-bf16 3-MFMA ----------------

#define LDK 136

__global__ __launch_bounds__(256) void gemm_mfma(const float* __restrict__ A,
                                                 const unsigned short* __restrict__ WtHi,
                                                 const unsigned short* __restrict__ WtLo,
                                                 __half* __restrict__ O, int M) {
  __shared__ unsigned short sHi[128 * LDK];
  __shared__ unsigned short sLo[128 * LDK];
  int tid = threadIdx.x;
#pragma unroll
  for (int i = 0; i < 8; ++i) {
    int c = tid + i * 256;
    int n = c >> 4;
    int off = (c & 15) * 8;
    *(ushort8*)&sHi[n * LDK + off] = *(const ushort8*)&WtHi[c * 8];
    *(ushort8*)&sLo[n * LDK + off] = *(const ushort8*)&WtLo[c * 8];
  }
  __syncthreads();

  int wv = tid >> 6, lane = tid & 63;
  int r0 = blockIdx.x * 128 + wv * 32;
  int lrow = lane & 15, lk = (lane >> 4) * 8;

  f32x4 acc[2][8] = {};
#pragma unroll
  for (int kk = 0; kk < 4; ++kk) {
    int k0 = kk * 32 + lk;
    short8 ahi[2], alo[2];
#pragma unroll
    for (int fr = 0; fr < 2; ++fr) {
      int row = r0 + fr * 16 + lrow;
      row = row < M ? row : M - 1;
      const float* ap = &A[(size_t)row * 128 + k0];
      float4 a0 = *(const float4*)ap;
      float4 a1 = *(const float4*)(ap + 4);
      union { short8 v; unsigned u32[4]; } h_, l_;
#define SPLIT2(slot, x, y)                              \
      {                                                 \
        unsigned hh = pk_bf16((x), (y));                \
        h_.u32[slot] = hh;                              \
        float hf0 = __uint_as_float(hh << 16);          \
        float hf1 = __uint_as_float(hh & 0xFFFF0000u);  \
        l_.u32[slot] = pk_bf16((x) - hf0, (y) - hf1);   \
      }
      SPLIT2(0, a0.x, a0.y)
      SPLIT2(1, a0.z, a0.w)
      SPLIT2(2, a1.x, a1.y)
      SPLIT2(3, a1.z, a1.w)
#undef SPLIT2
      ahi[fr] = h_.v;
      alo[fr] = l_.v;
    }
#pragma unroll
    for (int c = 0; c < 8; ++c) {
      int bidx = (c * 16 + lrow) * LDK + k0;
      short8 bhi = *(const short8*)&sHi[bidx];
      short8 blo = *(const short8*)&sLo[bidx];
#pragma unroll
      for (int fr = 0; fr < 2; ++fr) {
        acc[fr][c] = __builtin_amdgcn_mfma_f32_16x16x32_bf16(ahi[fr], bhi, acc[fr][c], 0, 0, 0);
        acc[fr][c] = __builtin_amdgcn_mfma_f32_16x16x32_bf16(ahi[fr], blo, acc[fr][c], 0, 0, 0);
        acc[fr][c] = __builtin_amdgcn_mfma_f32_16x16x32_bf16(alo[fr], bhi, acc[fr][c], 0, 0, 0);
      }
    }
  }
#pragma unroll
  for (int fr = 0; fr < 2; ++fr) {
#pragma unroll
    for (int c = 0; c < 8; ++c) {
#pragma unroll
      for (int r = 0; r < 4; ++r) {
        int row = r0 + fr * 16 + (lane >> 4) * 4 + r;
        if (row < M)
          O[(size_t)row * 128 + c * 16 + (lane & 15)] = __float2half(acc[fr][c][r]);
      }
    }
  }
}

// ---------------- layers 1-3 GEMM: fp16 A, W = Whi + Wlo*2^-10 ----------------

__global__ __launch_bounds__(256) void gemm_f16(const __half* __restrict__ Hf,
                                                const unsigned short* __restrict__ Whi,
                                                const unsigned short* __restrict__ Wlo,
                                                __half* __restrict__ O, int M) {
  __shared__ unsigned short sHi[128 * LDK];
  __shared__ unsigned short sLo[128 * LDK];
  int tid = threadIdx.x;
#pragma unroll
  for (int i = 0; i < 8; ++i) {
    int c = tid + i * 256;
    int n = c >> 4;
    int off = (c & 15) * 8;
    *(ushort8*)&sHi[n * LDK + off] = *(const ushort8*)&Whi[c * 8];
    *(ushort8*)&sLo[n * LDK + off] = *(const ushort8*)&Wlo[c * 8];
  }
  __syncthreads();

  int wv = tid >> 6, lane = tid & 63;
  int r0 = blockIdx.x * 128 + wv * 32;
  int lrow = lane & 15, lk = (lane >> 4) * 8;

  f32x4 acc[2][8] = {};
  f32x4 accL[2][8] = {};
#pragma unroll
  for (int kk = 0; kk < 4; ++kk) {
    int k0 = kk * 32 + lk;
    f16x8 a[2];
#pragma unroll
    for (int fr = 0; fr < 2; ++fr) {
      int row = r0 + fr * 16 + lrow;
      row = row < M ? row : M - 1;
      a[fr] = *(const f16x8*)&Hf[(size_t)row * 128 + k0];
    }
#pragma unroll
    for (int c = 0; c < 8; ++c) {
      int bidx = (c * 16 + lrow) * LDK + k0;
      f16x8 bhi = *(const f16x8*)&sHi[bidx];
      f16x8 blo = *(const f16x8*)&sLo[bidx];
#pragma unroll
      for (int fr = 0; fr < 2; ++fr) {
        acc[fr][c] = __builtin_amdgcn_mfma_f32_16x16x32_f16(a[fr], bhi, acc[fr][c], 0, 0, 0);
        accL[fr][c] = __builtin_amdgcn_mfma_f32_16x16x32_f16(a[fr], blo, accL[fr][c], 0, 0, 0);
      }
    }
  }
  const float ls = 1.0f / 1024.0f;
#pragma unroll
  for (int fr = 0; fr < 2; ++fr) {
#pragma unroll
    for (int c = 0; c < 8; ++c) {
#pragma unroll
      for (int r = 0; r < 4; ++r) {
        int row = r0 + fr * 16 + (lane >> 4) * 4 + r;
        if (row < M)
          O[(size_t)row * 128 + c * 16 + (lane & 15)] =
              __float2half(acc[fr][c][r] + accL[fr][c][r] * ls);
      }
    }
  }
}

// ---------------- fused gather + self-loop + bias + tanh ----------------
// FINAL=false: write fp16 Hf (next GEMM input). FINAL=true: write bf16 hi/lo
// pairs (pooling precision).

template <bool FINAL>
__global__ __launch_bounds__(256) void gather_k(const __half* __restrict__ h,
                                                const int* __restrict__ rs,
                                                const int2* __restrict__ edata,
                                                const float* __restrict__ dinv2,
                                                const float* __restrict__ bias,
                                                __half* __restrict__ Hf,
                                                unsigned* __restrict__ OHi,
                                                unsigned* __restrict__ OLo, int N) {
  int wid = (int)((blockIdx.x * (size_t)blockDim.x + threadIdx.x) >> 6);
  if (wid >= N) return;
  int lane = threadIdx.x & 63;
  int grp = lane >> 4;   // 0..3: edge slot
  int li = lane & 15;    // feature chunk: features [li*8, li*8+8)
  int s = rs[wid], e = rs[wid + 1];
  const uint4* hrow = (const uint4*)h;  // row i = hrow[i*16 + li]

  float ac[8] = {};
  int n16 = (e - s) >> 4;
  int base = s + grp;
#define ACC(U, W)                                        \
  {                                                      \
    FM_LO(ac[0], (U).x, (W)); FM_HI(ac[1], (U).x, (W));  \
    FM_LO(ac[2], (U).y, (W)); FM_HI(ac[3], (U).y, (W));  \
    FM_LO(ac[4], (U).z, (W)); FM_HI(ac[5], (U).z, (W));  \
    FM_LO(ac[6], (U).w, (W)); FM_HI(ac[7], (U).w, (W));  \
  }
  for (int it = 0; it < n16; ++it, base += 16) {
    int2 e0 = edata[base], e1 = edata[base + 4], e2 = edata[base + 8],
         e3 = edata[base + 12];
    float w0 = __int_as_float(e0.y), w1 = __int_as_float(e1.y),
          w2 = __int_as_float(e2.y), w3 = __int_as_float(e3.y);
    uint4 v0 = hrow[(size_t)e0.x * 16 + li];
    uint4 v1 = hrow[(size_t)e1.x * 16 + li];
    uint4 v2 = hrow[(size_t)e2.x * 16 + li];
    uint4 v3 = hrow[(size_t)e3.x * 16 + li];
    ACC(v0, w0) ACC(v1, w1) ACC(v2, w2) ACC(v3, w3)
  }
  for (int idx = base; idx < e; idx += 4) {
    int2 ed = edata[idx];
    float w = __int_as_float(ed.y);
    uint4 v = hrow[(size_t)ed.x * 16 + li];
    ACC(v, w)
  }
#undef ACC
#pragma unroll
  for (int j = 0; j < 8; ++j) {
    ac[j] += __shfl_xor(ac[j], 16);
    ac[j] += __shfl_xor(ac[j], 32);
  }

  // group g finalizes features {li*8+2g, li*8+2g+1}
  float a0 = grp == 0 ? ac[0] : grp == 1 ? ac[2] : grp == 2 ? ac[4] : ac[6];
  float a1 = grp == 0 ? ac[1] : grp == 1 ? ac[3] : grp == 2 ? ac[5] : ac[7];

  float d2 = dinv2[wid];
  uint4 sv = hrow[(size_t)wid * 16 + li];
  unsigned su = grp == 0 ? sv.x : grp == 1 ? sv.y : grp == 2 ? sv.z : sv.w;
  float2 sj = __half22float2(*(__half2*)&su);
  float2 bj = *(const float2*)&bias[li * 8 + 2 * grp];
  float o0 = fast_tanh(a0 + sj.x * d2 + bj.x);
  float o1 = fast_tanh(a1 + sj.y * d2 + bj.y);

  if (FINAL) {
    unsigned hp = pk_bf16(o0, o1);
    float r0f = __uint_as_float(hp << 16);
    float r1f = __uint_as_float(hp & 0xFFFF0000u);
    unsigned lp = pk_bf16(o0 - r0f, o1 - r1f);
    unsigned idx = (unsigned)wid * 64 + li * 4 + grp;
    OHi[idx] = hp;
    OLo[idx] = lp;
  } else {
    __half2 hv = __float22half2_rn(make_float2(o0, o1));
    *(__half2*)&Hf[(size_t)wid * 128 + li * 8 + 2 * grp] = hv;
  }
}

// ---------------- pooling ----------------

#define CH 16

__global__ __launch_bounds__(128) void pool_partial(const unsigned short* __restrict__ Hi,
                                                    const unsigned short* __restrict__ Lo,
                                                    const int* __restrict__ gstart,
                                                    float* __restrict__ pmax,
                                                    float* __restrict__ psum) {
  int g = blockIdx.x, c = blockIdx.y, f = threadIdx.x;
  int s = gstart[g], e = gstart[g + 1];
  long long len = e - s;
  int cs = s + (int)(len * c / CH);
  int ce = s + (int)(len * (c + 1) / CH);
  float m = -INFINITY, sum = 0.f;
  for (int n = cs; n < ce; ++n) {
    unsigned hv = Hi[(size_t)n * 128 + f];
    unsigned lv = Lo[(size_t)n * 128 + f];
    float v = __uint_as_float(hv << 16) + __uint_as_float(lv << 16);
    m = fmaxf(m, v);
    sum += v;
  }
  pmax[((size_t)g * CH + c) * 128 + f] = m;
  psum[((size_t)g * CH + c) * 128 + f] = sum;
}

__global__ __launch_bounds__(128) void pool_head(const float* __restrict__ pmax,
                                                 const float* __restrict__ psum,
                                                 const int* __restrict__ gstart,
                                                 const float* __restrict__ Wout,
                                                 const float* __restrict__ bout,
                                                 float* __restrict__ out, int G) {
  __shared__ float pl[256];
  int g = blockIdx.x, f = threadIdx.x;
  float m = -INFINITY, s = 0.f;
  for (int c = 0; c < CH; ++c) {
    m = fmaxf(m, pmax[((size_t)g * CH + c) * 128 + f]);
    s += psum[((size_t)g * CH + c) * 128 + f];
  }
  int cnt = gstart[g + 1] - gstart[g];
  float mean = s / fmaxf((float)cnt, 1.0f);
  float* pooled = out + (size_t)G * 10;
  pooled[(size_t)g * 256 + f] = m;
  pooled[(size_t)g * 256 + 128 + f] = mean;
  pl[f] = m;
  pl[128 + f] = mean;
  __syncthreads();
  if (f < 10) {
    float acc = bout[f];
    for (int k = 0; k < 256; ++k) acc += pl[k] * Wout[k * 10 + f];
    out[(size_t)g * 10 + f] = acc;
  }
}

// ---------------- launch ----------------

extern "C" void kernel_launch(void* const* d_in, const int* in_sizes, int n_in,
                              void* d_out, int out_size, void* d_ws, size_t ws_size,
                              hipStream_t stream) {
  const float* x = (const float*)d_in[0];
  const int* ei = (const int*)d_in[1];
  const int* batch = (const int*)d_in[2];
  const float* W[4] = {(const float*)d_in[3], (const float*)d_in[5],
                       (const float*)d_in[7], (const float*)d_in[9]};
  const float* Bz[4] = {(const float*)d_in[4], (const float*)d_in[6],
                        (const float*)d_in[8], (const float*)d_in[10]};
  const float* Wout = (const float*)d_in[11];
  const float* bout = (const float*)d_in[12];
  const int N = in_sizes[0] / 128;
  const int E = in_sizes[1] / 2;
  const int G = 64;
  const int* srcp = ei;
  const int* dstp = ei + E;
  float* out = (float*)d_out;

  char* wsb = (char*)d_ws;
  size_t off = 0;
  auto alloc = [&](size_t bytes) -> void* {
    void* p = wsb + off;
    off = (off + bytes + 255) & ~(size_t)255;
    return p;
  };
  __half* bufA = (__half*)alloc((size_t)N * 128 * 2);    // GEMM out (fp16)
  __half* Hf = (__half*)alloc((size_t)N * 128 * 2);      // gather out (fp16)
  unsigned* OHi = (unsigned*)alloc((size_t)N * 64 * 4);  // final bf16-hi pairs
  unsigned* OLo = (unsigned*)alloc((size_t)N * 64 * 4);  // final bf16-lo pairs
  int* cnt = (int*)alloc((size_t)N * 4);
  int* epos = (int*)alloc((size_t)E * 4);
  float* dinv = (float*)alloc((size_t)N * 4);
  float* dinv2 = (float*)alloc((size_t)N * 4);
  int* rs = (int*)alloc((size_t)(N + 1) * 4);
  int2* edata = (int2*)alloc((size_t)E * 8);
  int* bsum = (int*)alloc(4096);
  int* boff = (int*)alloc(4096);
  int* gstart = (int*)alloc(4096);
  float* pmax = (float*)alloc((size_t)G * CH * 128 * 4);
  float* psum = (float*)alloc((size_t)G * CH * 128 * 4);
  unsigned short* Wt0Hi = (unsigned short*)alloc(16384 * 2);
  unsigned short* Wt0Lo = (unsigned short*)alloc(16384 * 2);
  unsigned short* WfHi = (unsigned short*)alloc(3 * 16384 * 2);
  unsigned short* WfLo = (unsigned short*)alloc(3 * 16384 * 2);
  if (off > ws_size) return;

  hipMemsetAsync(cnt, 0, (size_t)N * 4, stream);

  count_k<<<(E + 255) / 256, 256, 0, stream>>>(dstp, cnt, epos, E);
  int nsb = (N + 511) / 512;
  scan_a<<<nsb, 512, 0, stream>>>(cnt, rs, bsum, dinv, dinv2, N);
  scan_b<<<1, 256, 0, stream>>>(bsum, boff, nsb, batch, gstart, N, G);
  scan_c<<<nsb, 512, 0, stream>>>(boff, rs, N, E);
  fill_k<<<(E + 255) / 256, 256, 0, stream>>>(srcp, dstp, rs, epos, dinv, edata, E);
  wconv_all<<<dim3(32, 4), 256, 0, stream>>>(W[0], W[1], W[2], W[3], Wt0Hi, Wt0Lo,
                                             WfHi, WfLo);

  int ggrid = (int)(((size_t)N * 64 + 255) / 256);
  for (int l = 0; l < 4; ++l) {
    if (l == 0)
      gemm_mfma<<<(N + 127) / 128, 256, 0, stream>>>(x, Wt0Hi, Wt0Lo, bufA, N);
    else
      gemm_f16<<<(N + 127) / 128, 256, 0, stream>>>(Hf, WfHi + (l - 1) * 16384,
                                                    WfLo + (l - 1) * 16384, bufA, N);
    if (l < 3)
      gather_k<false><<<ggrid, 256, 0, stream>>>(bufA, rs, edata, dinv2, Bz[l], Hf,
                                                 OHi, OLo, N);
    else
      gather_k<true><<<ggrid, 256, 0, stream>>>(bufA, rs, edata, dinv2, Bz[l], Hf,
                                                OHi, OLo, N);
  }

  pool_partial<<<dim3(G, CH), 128, 0, stream>>>((const unsigned short*)OHi,
                                                (const unsigned short*)OLo, gstart,
                                                pmax, psum);
  pool_head<<<G, 128, 0, stream>>>(pmax, psum, gstart, Wout, bout, out, G);
}